// Round 14
// baseline (443.004 us; speedup 1.0000x reference)
//
#include <hip/hip_runtime.h>
#include <hip/hip_bf16.h>
#include <stdint.h>

#define T_DIM 2048
#define B_DIM 4
#define E_DIM 1024
#define H_DIM 16
#define EHD 64
#define L2E 1.4426950408889634f
#define QSCALE (0.125f * L2E)
#define FMAXC 12.0f

typedef __attribute__((ext_vector_type(8))) short bf16x8;
typedef __attribute__((ext_vector_type(4))) float f32x4;
typedef __attribute__((ext_vector_type(2))) float f32x2;
typedef __attribute__((ext_vector_type(2))) unsigned u32x2;

__device__ __forceinline__ unsigned short f2bf(float x) {
  unsigned int u = __builtin_bit_cast(unsigned int, x);
  u += 0x7fffu + ((u >> 16) & 1u);
  return (unsigned short)(u >> 16);
}

__device__ __forceinline__ unsigned pkbf(float a, float b) {
  return (unsigned)f2bf(a) | ((unsigned)f2bf(b) << 16);
}

// fast half-up pack (attn hot loop only): 5 ops/pair, bias < 2^-10 rel.
__device__ __forceinline__ unsigned pkbf2(float a, float b) {
  unsigned ua = __builtin_bit_cast(unsigned, a) + 0x8000u;
  unsigned ub = __builtin_bit_cast(unsigned, b) + 0x8000u;
  return (ua >> 16) | (ub & 0xffff0000u);
}

__device__ __forceinline__ f32x2 bfpair(unsigned w) {
  u32x2 u = {w << 16, w & 0xffff0000u};
  return __builtin_bit_cast(f32x2, u);
}

__device__ __forceinline__ void gload16(const void* g, void* l) {
  __builtin_amdgcn_global_load_lds(
      (const __attribute__((address_space(1))) void*)g,
      (__attribute__((address_space(3))) void*)l, 16, 0, 0);
}

// ---------------- fp32 -> bf16 ----------------
__global__ __launch_bounds__(256) void cvt_kernel(const float4* __restrict__ in,
                                                  uint2* __restrict__ out, int n4) {
  int i = blockIdx.x * 256 + threadIdx.x;
  int stride = gridDim.x * 256;
  for (; i < n4; i += stride) {
    float4 f = in[i];
    uint2 o;
    o.x = pkbf(f.x, f.y);
    o.y = pkbf(f.z, f.w);
    out[i] = o;
  }
}

// ---------------- 128x128 bf16 NT GEMM (m97 structure + XCD swizzle) --------
template <int MODE>
__global__ __launch_bounds__(256) void gemm_kernel(
    const unsigned short* __restrict__ Abase,
    const unsigned short* __restrict__ Bt,
    const float* __restrict__ bias,
    void* __restrict__ outv, int K) {
  __shared__ alignas(16) short As[128 * 32];
  __shared__ alignas(16) short Bs[128 * 32];
  const int tid = threadIdx.x;
  const int lane = tid & 63, wave = tid >> 6;
  // XCD-aware bijective swizzle (T1): nwg = 64*gridDim.y, always %8==0 here.
  const int lin = blockIdx.y * 64 + blockIdx.x;
  const int cpx = (gridDim.y << 6) >> 3;
  const int swz = (lin & 7) * cpx + (lin >> 3);
  const int m0 = (swz & 63) * 128, n0 = (swz >> 6) * 128;
  const int wr = wave >> 1, wc = wave & 1;
  const int lrow = lane & 15, lgrp = lane >> 4;

  const unsigned short* A = Abase;
  if (MODE == 0) A += (size_t)(n0 >> 10) * (8192u * 1024u);

  f32x4 acc[4][4];
#pragma unroll
  for (int m = 0; m < 4; ++m)
#pragma unroll
    for (int n = 0; n < 4; ++n) acc[m][n] = (f32x4){0.f, 0.f, 0.f, 0.f};

  const int srow = wave * 16 + (lane >> 2);
  const int scol = (lane & 3) * 8;
  short* lA0 = As + wave * 16 * 32;
  short* lA1 = As + (64 + wave * 16) * 32;
  short* lB0 = Bs + wave * 16 * 32;
  short* lB1 = Bs + (64 + wave * 16) * 32;

  for (int k0 = 0; k0 < K; k0 += 32) {
    const unsigned short* ga = A + (size_t)(m0 + srow) * K + k0 + scol;
    const unsigned short* gb = Bt + (size_t)(n0 + srow) * K + k0 + scol;
    gload16(ga, lA0);
    gload16(ga + (size_t)64 * K, lA1);
    gload16(gb, lB0);
    gload16(gb + (size_t)64 * K, lB1);
    __syncthreads();
    const short* pa = As + (wr * 64 + lrow) * 32 + lgrp * 8;
    const short* pb = Bs + (wc * 64 + lrow) * 32 + lgrp * 8;
    bf16x8 a[4], b[4];
#pragma unroll
    for (int m = 0; m < 4; ++m) a[m] = *(const bf16x8*)(pa + m * 512);
#pragma unroll
    for (int n = 0; n < 4; ++n) b[n] = *(const bf16x8*)(pb + n * 512);
#pragma unroll
    for (int m = 0; m < 4; ++m)
#pragma unroll
      for (int n = 0; n < 4; ++n)
        acc[m][n] = __builtin_amdgcn_mfma_f32_16x16x32_bf16(a[m], b[n], acc[m][n], 0, 0, 0);
    __syncthreads();
  }

#pragma unroll
  for (int n = 0; n < 4; ++n) {
    const int gn = n0 + wc * 64 + n * 16 + lrow;
    const float bv = bias[gn];
    if (MODE == 0) {
      unsigned short* out = (unsigned short*)outv;
      const int which = gn >> 10;
      const float qsc = (which == 0) ? QSCALE : 1.0f;
      const int e = gn & 1023;
      const int hh = e >> 6, dd = e & 63;
#pragma unroll
      for (int m = 0; m < 4; ++m)
#pragma unroll
        for (int r = 0; r < 4; ++r) {
          const int gm = m0 + wr * 64 + m * 16 + lgrp * 4 + r;
          const int t = gm >> 2, bb = gm & 3;  // A row index is t*B + b
          const unsigned short val = f2bf((acc[m][n][r] + bv) * qsc);
          if (which == 2) {
            out[((size_t)(2 * B_DIM * H_DIM) + bb * H_DIM + hh) * (T_DIM * EHD) +
                (size_t)(t >> 6) * 4096 + dd * 64 + (t & 63)] = val;
          } else {
            out[((size_t)which * B_DIM * H_DIM + bb * H_DIM + hh) * (T_DIM * EHD) +
                (size_t)t * EHD + dd] = val;
          }
        }
    } else {
      float* out = (float*)outv;
#pragma unroll
      for (int m = 0; m < 4; ++m)
#pragma unroll
        for (int r = 0; r < 4; ++r) {
          const int gm = m0 + wr * 64 + m * 16 + lgrp * 4 + r;  // row = b*T + t
          const int bb = gm >> 11, t = gm & 2047;
          out[((size_t)t * B_DIM + bb) * E_DIM + gn] = acc[m][n][r] + bv;
        }
    }
  }
}

// ---------------- flash attention: barrier-free, pinned prefetch ------------
// grid (T/128, B*H), 4 waves, 2 q-groups/wave (q=lrow). Fixed-max softmax.
// ZERO block barriers: per wave, K+mask in registers (double-buffered,
// issued at ITER START, pinned by sched_barrier -> 1-iter issue-to-use
// distance), V in per-wave LDS quarter via global_load_lds (single buffer,
// staged after PV, WAR via lgkmcnt(0)). Round-13 failed because the compiler
// sank end-of-iter loads to their uses (VGPR=76 proved it) and mask loads
// were youngest -> auto vmcnt(0) drain/iter. Static wait ladder now:
//   issue order: KM(t+1) [start of t] ... V(t+1) [end of t] ... KM(t+2)
//   QK(t): auto vmcnt(32); softmax(t): auto vmcnt(24)
//   PV(t): explicit vmcnt(16) retires V(t)      (vmcnt(0) on last iter)
__global__ __launch_bounds__(256) void attn_kernel(
    const unsigned short* __restrict__ Qm, const unsigned short* __restrict__ Km,
    const unsigned short* __restrict__ Vtm, const unsigned short* __restrict__ Mb,
    unsigned short* __restrict__ ctx) {
  __shared__ alignas(16) short Vs[4][4096];
  __shared__ alignas(16) short Pl[4][2][1024];
  const int tid = threadIdx.x, lane = tid & 63, wave = tid >> 6;
  const int lrow = lane & 15, lgrp = lane >> 4;
  const int bh = blockIdx.y, b = bh >> 4, h = bh & 15;
  const int q0 = blockIdx.x * 128;

  const size_t base = (size_t)bh * (T_DIM * EHD);

  bf16x8 qf0[2], qf1[2];
  int qrow[2];
  const unsigned short* mb[2];
#pragma unroll
  for (int g = 0; g < 2; ++g) {
    qrow[g] = q0 + g * 64 + wave * 16 + lrow;
    const unsigned short* qp = Qm + base + (size_t)qrow[g] * EHD + lgrp * 8;
    qf0[g] = *(const bf16x8*)qp;
    qf1[g] = *(const bf16x8*)(qp + 32);
    mb[g] = Mb + (size_t)qrow[g] * T_DIM + lgrp * 4;
  }

  f32x4 oacc[2][4];
#pragma unroll
  for (int g = 0; g < 2; ++g)
#pragma unroll
    for (int n = 0; n < 4; ++n) oacc[g][n] = (f32x4){0.f, 0.f, 0.f, 0.f};
  f32x2 racc[2] = {(f32x2){0.f, 0.f}, (f32x2){0.f, 0.f}};

  const int rr = lane >> 3;
  const int cs = (((lane & 7) ^ rr) * 8);
  const int rx = (lrow & 7) * 8;

  const unsigned short* kb_g = Km + base + (size_t)lrow * EHD + lgrp * 8;
  const unsigned short* vsb = Vtm + base + (size_t)rr * 64 + cs;
  short* vdst = Vs[wave];
  short* plw0 = &Pl[wave][0][lrow * 64];
  short* plw1 = &Pl[wave][1][lrow * 64];

  bf16x8 kreg[2][4][2];   // [parity][n][chunk]
  uint2 mreg[2][2][4];    // [parity][group][n]

#define STAGE_V(T)                                                              \
  {                                                                             \
    _Pragma("unroll") for (int i = 0; i < 8; ++i) {                             \
      gload16(vsb + (size_t)(T) * 4096 + i * 512, vdst + i * 512);              \
    }                                                                           \
  }

#define LOAD_KM(P, T)                                                           \
  {                                                                             \
    _Pragma("unroll") for (int n = 0; n < 4; ++n) {                             \
      kreg[P][n][0] = *(const bf16x8*)(kb_g + (size_t)(T) * 4096 + n * 1024);   \
      kreg[P][n][1] =                                                           \
          *(const bf16x8*)(kb_g + (size_t)(T) * 4096 + n * 1024 + 32);          \
    }                                                                           \
    _Pragma("unroll") for (int g = 0; g < 2; ++g) {                             \
      _Pragma("unroll") for (int n = 0; n < 4; ++n) {                           \
        mreg[P][g][n] = *(const uint2*)(mb[g] + (T) * 64 + n * 16);             \
      }                                                                         \
    }                                                                           \
  }

// QK^T + softmax for tile t (parity CUR); optionally first issue KM(t+1).
#define ATTN_TOP(CUR, DO_PRE, TN)                                               \
  {                                                                             \
    if (DO_PRE) {                                                               \
      LOAD_KM((CUR) ^ 1, TN);                                                   \
      __builtin_amdgcn_sched_barrier(0); /* pin issue before QK */              \
    }                                                                           \
    float sv[2][4][4];                                                          \
    __builtin_amdgcn_s_setprio(1);                                              \
    _Pragma("unroll") for (int n = 0; n < 4; ++n) {                             \
      f32x4 s0 = (f32x4){0.f, 0.f, 0.f, 0.f}, s1 = s0;                          \
      s0 = __builtin_amdgcn_mfma_f32_16x16x32_bf16(kreg[CUR][n][0], qf0[0], s0, 0, 0, 0); \
      s0 = __builtin_amdgcn_mfma_f32_16x16x32_bf16(kreg[CUR][n][1], qf1[0], s0, 0, 0, 0); \
      s1 = __builtin_amdgcn_mfma_f32_16x16x32_bf16(kreg[CUR][n][0], qf0[1], s1, 0, 0, 0); \
      s1 = __builtin_amdgcn_mfma_f32_16x16x32_bf16(kreg[CUR][n][1], qf1[1], s1, 0, 0, 0); \
      _Pragma("unroll") for (int r = 0; r < 4; ++r) {                           \
        sv[0][n][r] = s0[r];                                                    \
        sv[1][n][r] = s1[r];                                                    \
      }                                                                         \
    }                                                                           \
    __builtin_amdgcn_s_setprio(0);                                              \
    _Pragma("unroll") for (int g = 0; g < 2; ++g) {                             \
      short* plw = g ? plw1 : plw0;                                             \
      _Pragma("unroll") for (int n = 0; n < 4; ++n) {                           \
        const uint2 mw = mreg[CUR][g][n];                                       \
        const f32x2 s01 = {sv[g][n][0], sv[g][n][1]};                           \
        const f32x2 s23 = {sv[g][n][2], sv[g][n][3]};                           \
        const f32x2 t01 = __builtin_elementwise_fma(                            \
            s01, bfpair(mw.x), (f32x2){-FMAXC, -FMAXC});                        \
        const f32x2 t23 = __builtin_elementwise_fma(                            \
            s23, bfpair(mw.y), (f32x2){-FMAXC, -FMAXC});                        \
        const float p0 = __builtin_amdgcn_exp2f(t01.x);                         \
        const float p1 = __builtin_amdgcn_exp2f(t01.y);                         \
        const float p2 = __builtin_amdgcn_exp2f(t23.x);                         \
        const float p3 = __builtin_amdgcn_exp2f(t23.y);                         \
        racc[g] += (f32x2){p0, p1} + (f32x2){p2, p3};                           \
        uint2 w;                                                                \
        w.x = pkbf2(p0, p1);                                                    \
        w.y = pkbf2(p2, p3);                                                    \
        *(uint2*)(plw + ((n * 16 + lgrp * 4) ^ rx)) = w;                        \
      }                                                                         \
    }                                                                           \
  }

// PV for tile t; optionally re-stage V(t+1) into this wave's buffer.
#define ATTN_BOT(CUR, DO_PRE, TN)                                               \
  {                                                                             \
    __builtin_amdgcn_s_setprio(1);                                              \
    _Pragma("unroll") for (int kc = 0; kc < 2; ++kc) {                          \
      const int pc = ((kc * 32) + lgrp * 8) ^ rx;                               \
      const bf16x8 pB0 = *(const bf16x8*)(plw0 + pc);                           \
      const bf16x8 pB1 = *(const bf16x8*)(plw1 + pc);                           \
      _Pragma("unroll") for (int n = 0; n < 4; ++n) {                           \
        const bf16x8 vf = *(const bf16x8*)(vdst + (n * 16 + lrow) * 64 + pc);   \
        oacc[0][n] = __builtin_amdgcn_mfma_f32_16x16x32_bf16(vf, pB0, oacc[0][n], 0, 0, 0); \
        oacc[1][n] = __builtin_amdgcn_mfma_f32_16x16x32_bf16(vf, pB1, oacc[1][n], 0, 0, 0); \
      }                                                                         \
    }                                                                           \
    __builtin_amdgcn_s_setprio(0);                                              \
    if (DO_PRE) {                                                               \
      asm volatile("s_waitcnt lgkmcnt(0)" ::: "memory"); /* WAR on Vs */        \
      __builtin_amdgcn_sched_barrier(0);                                        \
      STAGE_V(TN);                                                              \
      __builtin_amdgcn_sched_barrier(0);                                        \
    }                                                                           \
  }

#define WAITV(N)                                                                \
  __builtin_amdgcn_sched_barrier(0);                                            \
  asm volatile("s_waitcnt vmcnt(" #N ")" ::: "memory");                         \
  __builtin_amdgcn_sched_barrier(0);

  // prologue: KM(0) then V(0)  (V younger -- wait ladder counts assume this)
  LOAD_KM(0, 0);
  __builtin_amdgcn_sched_barrier(0);
  STAGE_V(0);
  __builtin_amdgcn_sched_barrier(0);

  for (int tt = 0; tt < 15; ++tt) {
    ATTN_TOP(0, 1, 2 * tt + 1) WAITV(16) ATTN_BOT(0, 1, 2 * tt + 1)
    ATTN_TOP(1, 1, 2 * tt + 2) WAITV(16) ATTN_BOT(1, 1, 2 * tt + 2)
  }
  ATTN_TOP(0, 1, 31) WAITV(16) ATTN_BOT(0, 1, 31)   // t = 30
  ATTN_TOP(1, 0, 0) WAITV(0) ATTN_BOT(1, 0, 0)      // t = 31 (drain V(31))

#undef ATTN_TOP
#undef ATTN_BOT
#undef WAITV
#undef LOAD_KM
#undef STAGE_V

#pragma unroll
  for (int g = 0; g < 2; ++g) {
    float lr = racc[g].x + racc[g].y;
    lr += __shfl_xor(lr, 16);
    lr += __shfl_xor(lr, 32);
    const float inv = 1.f / lr;
    unsigned short* cp =
        ctx + ((size_t)b * T_DIM + qrow[g]) * E_DIM + h * EHD + lgrp * 4;
#pragma unroll
    for (int n = 0; n < 4; ++n) {
      uint2 w;
      w.x = pkbf2(oacc[g][n][0] * inv, oacc[g][n][1] * inv);
      w.y = pkbf2(oacc[g][n][2] * inv, oacc[g][n][3] * inv);
      *(uint2*)(cp + n * 16) = w;
    }
  }
}

extern "C" void kernel_launch(void* const* d_in, const int* in_sizes, int n_in,
                              void* d_out, int out_size, void* d_ws, size_t ws_size,
                              hipStream_t stream) {
  const float* q    = (const float*)d_in[0];
  const float* k    = (const float*)d_in[1];
  const float* v    = (const float*)d_in[2];
  const float* mask = (const float*)d_in[3];
  const float* wqkv = (const float*)d_in[4];
  const float* bqkv = (const float*)d_in[5];
  const float* wout = (const float*)d_in[6];
  const float* bout = (const float*)d_in[7];

  char* ws = (char*)d_ws;
  unsigned short* Xb   = (unsigned short*)(ws);
  unsigned short* Wqb  = (unsigned short*)(ws + 50331648);
  unsigned short* Wob  = (unsigned short*)(ws + 56623104);
  unsigned short* QKVb = (unsigned short*)(ws + 58720256);  // [Q|K|Vt] bf16
  unsigned short* CTXb = (unsigned short*)(ws);             // [B][T][E] (Xb dead)
  unsigned short* Mb   = (unsigned short*)(ws + 16777216);  // bf16 mask, in dead Xb

  cvt_kernel<<<2048, 256, 0, stream>>>((const float4*)q, (uint2*)Xb, 2097152);
  cvt_kernel<<<2048, 256, 0, stream>>>((const float4*)k, (uint2*)(Xb + 8388608), 2097152);
  cvt_kernel<<<2048, 256, 0, stream>>>((const float4*)v, (uint2*)(Xb + 16777216), 2097152);
  cvt_kernel<<<1024, 256, 0, stream>>>((const float4*)wqkv, (uint2*)Wqb, 786432);
  cvt_kernel<<<512, 256, 0, stream>>>((const float4*)wout, (uint2*)Wob, 262144);

  gemm_kernel<0><<<dim3(64, 24), 256, 0, stream>>>(Xb, Wqb, bqkv, QKVb, 1024);
  // mask -> bf16 AFTER GEMM1 (Mb lives in the then-dead Xb region)
  cvt_kernel<<<1024, 256, 0, stream>>>((const float4*)mask, (uint2*)Mb, 1048576);
  attn_kernel<<<dim3(16, 64), 256, 0, stream>>>(QKVb, QKVb + 8388608,
                                                QKVb + 16777216, Mb, CTXb);
  gemm_kernel<1><<<dim3(64, 8), 256, 0, stream>>>(CTXb, Wob, bout, d_out, 1024);
}

// Round 15
// 359.615 us; speedup vs baseline: 1.2319x; 1.2319x over previous
//
#include <hip/hip_runtime.h>
#include <hip/hip_bf16.h>
#include <stdint.h>

#define T_DIM 2048
#define B_DIM 4
#define E_DIM 1024
#define H_DIM 16
#define EHD 64
#define L2E 1.4426950408889634f
#define QSCALE (0.125f * L2E)
#define FMAXC 12.0f

typedef __attribute__((ext_vector_type(8))) short bf16x8;
typedef __attribute__((ext_vector_type(4))) float f32x4;
typedef __attribute__((ext_vector_type(2))) float f32x2;
typedef __attribute__((ext_vector_type(2))) unsigned u32x2;

__device__ __forceinline__ unsigned short f2bf(float x) {
  unsigned int u = __builtin_bit_cast(unsigned int, x);
  u += 0x7fffu + ((u >> 16) & 1u);
  return (unsigned short)(u >> 16);
}

__device__ __forceinline__ unsigned pkbf(float a, float b) {
  return (unsigned)f2bf(a) | ((unsigned)f2bf(b) << 16);
}

// fast half-up pack (attn hot loop only): 5 ops/pair, bias < 2^-10 rel.
__device__ __forceinline__ unsigned pkbf2(float a, float b) {
  unsigned ua = __builtin_bit_cast(unsigned, a) + 0x8000u;
  unsigned ub = __builtin_bit_cast(unsigned, b) + 0x8000u;
  return (ua >> 16) | (ub & 0xffff0000u);
}

__device__ __forceinline__ f32x2 bfpair(unsigned w) {
  u32x2 u = {w << 16, w & 0xffff0000u};
  return __builtin_bit_cast(f32x2, u);
}

__device__ __forceinline__ void gload16(const void* g, void* l) {
  __builtin_amdgcn_global_load_lds(
      (const __attribute__((address_space(1))) void*)g,
      (__attribute__((address_space(3))) void*)l, 16, 0, 0);
}

// ---------------- fp32 -> bf16 ----------------
__global__ __launch_bounds__(256) void cvt_kernel(const float4* __restrict__ in,
                                                  uint2* __restrict__ out, int n4) {
  int i = blockIdx.x * 256 + threadIdx.x;
  int stride = gridDim.x * 256;
  for (; i < n4; i += stride) {
    float4 f = in[i];
    uint2 o;
    o.x = pkbf(f.x, f.y);
    o.y = pkbf(f.z, f.w);
    out[i] = o;
  }
}

// ---------------- 128x128 bf16 NT GEMM (m97 structure, round-12 exact) ------
template <int MODE>
__global__ __launch_bounds__(256) void gemm_kernel(
    const unsigned short* __restrict__ Abase,
    const unsigned short* __restrict__ Bt,
    const float* __restrict__ bias,
    void* __restrict__ outv, int K) {
  __shared__ alignas(16) short As[128 * 32];
  __shared__ alignas(16) short Bs[128 * 32];
  const int tid = threadIdx.x;
  const int lane = tid & 63, wave = tid >> 6;
  const int m0 = blockIdx.x * 128, n0 = blockIdx.y * 128;
  const int wr = wave >> 1, wc = wave & 1;
  const int lrow = lane & 15, lgrp = lane >> 4;

  const unsigned short* A = Abase;
  if (MODE == 0) A += (size_t)(n0 >> 10) * (8192u * 1024u);

  f32x4 acc[4][4];
#pragma unroll
  for (int m = 0; m < 4; ++m)
#pragma unroll
    for (int n = 0; n < 4; ++n) acc[m][n] = (f32x4){0.f, 0.f, 0.f, 0.f};

  const int srow = wave * 16 + (lane >> 2);
  const int scol = (lane & 3) * 8;
  short* lA0 = As + wave * 16 * 32;
  short* lA1 = As + (64 + wave * 16) * 32;
  short* lB0 = Bs + wave * 16 * 32;
  short* lB1 = Bs + (64 + wave * 16) * 32;

  for (int k0 = 0; k0 < K; k0 += 32) {
    const unsigned short* ga = A + (size_t)(m0 + srow) * K + k0 + scol;
    const unsigned short* gb = Bt + (size_t)(n0 + srow) * K + k0 + scol;
    gload16(ga, lA0);
    gload16(ga + (size_t)64 * K, lA1);
    gload16(gb, lB0);
    gload16(gb + (size_t)64 * K, lB1);
    __syncthreads();
    const short* pa = As + (wr * 64 + lrow) * 32 + lgrp * 8;
    const short* pb = Bs + (wc * 64 + lrow) * 32 + lgrp * 8;
    bf16x8 a[4], b[4];
#pragma unroll
    for (int m = 0; m < 4; ++m) a[m] = *(const bf16x8*)(pa + m * 512);
#pragma unroll
    for (int n = 0; n < 4; ++n) b[n] = *(const bf16x8*)(pb + n * 512);
#pragma unroll
    for (int m = 0; m < 4; ++m)
#pragma unroll
      for (int n = 0; n < 4; ++n)
        acc[m][n] = __builtin_amdgcn_mfma_f32_16x16x32_bf16(a[m], b[n], acc[m][n], 0, 0, 0);
    __syncthreads();
  }

#pragma unroll
  for (int n = 0; n < 4; ++n) {
    const int gn = n0 + wc * 64 + n * 16 + lrow;
    const float bv = bias[gn];
    if (MODE == 0) {
      unsigned short* out = (unsigned short*)outv;
      const int which = gn >> 10;
      const float qsc = (which == 0) ? QSCALE : 1.0f;
      const int e = gn & 1023;
      const int hh = e >> 6, dd = e & 63;
#pragma unroll
      for (int m = 0; m < 4; ++m)
#pragma unroll
        for (int r = 0; r < 4; ++r) {
          const int gm = m0 + wr * 64 + m * 16 + lgrp * 4 + r;
          const int t = gm >> 2, bb = gm & 3;  // A row index is t*B + b
          const unsigned short val = f2bf((acc[m][n][r] + bv) * qsc);
          if (which == 2) {
            out[((size_t)(2 * B_DIM * H_DIM) + bb * H_DIM + hh) * (T_DIM * EHD) +
                (size_t)(t >> 6) * 4096 + dd * 64 + (t & 63)] = val;
          } else {
            out[((size_t)which * B_DIM * H_DIM + bb * H_DIM + hh) * (T_DIM * EHD) +
                (size_t)t * EHD + dd] = val;
          }
        }
    } else {
      float* out = (float*)outv;
#pragma unroll
      for (int m = 0; m < 4; ++m)
#pragma unroll
        for (int r = 0; r < 4; ++r) {
          const int gm = m0 + wr * 64 + m * 16 + lgrp * 4 + r;  // row = b*T + t
          const int bb = gm >> 11, t = gm & 2047;
          out[((size_t)t * B_DIM + bb) * E_DIM + gn] = acc[m][n][r] + bv;
        }
    }
  }
}

// ---------------- flash attention: QBLK=256, 4 q-groups/wave ----------------
// grid (T/256, B*H) = 512 blocks, 4 waves. Fixed-max softmax, bf16 mask,
// counted-vmcnt 2-phase staging (round-12 proven). Rationale: per-iteration
// wall (~3.4k cy) is ~3x summed pipe demand and invariant to occupancy /
// warmth / transactions / VALU count -> amortize the fixed per-iter overhead
// over 2x the q-rows. K fragments hoisted to registers ONCE per tile (8
// ds_read_b128 shared by 4 groups), V reads shared via group-fused PV ->
// 64 MFMA per wave-iter at ~same DS/latency cost. WAITBAR(16): retires the
// 4 STAGE DMAs, keeps 16 next-tile mask loads in flight. Never vmcnt(0).
__global__ __launch_bounds__(256, 2) void attn_kernel(
    const unsigned short* __restrict__ Qm, const unsigned short* __restrict__ Km,
    const unsigned short* __restrict__ Vtm, const unsigned short* __restrict__ Mb,
    unsigned short* __restrict__ ctx) {
  __shared__ alignas(16) short Ks[2][4096];
  __shared__ alignas(16) short Vs[2][4096];
  __shared__ alignas(16) short Pl[4][4][1024];
  const int tid = threadIdx.x, lane = tid & 63, wave = tid >> 6;
  const int lrow = lane & 15, lgrp = lane >> 4;
  const int bh = blockIdx.y, b = bh >> 4, h = bh & 15;
  const int q0 = blockIdx.x * 256;

  const size_t base = (size_t)bh * (T_DIM * EHD);

  bf16x8 qf0[4], qf1[4];
  int qrow[4];
  const unsigned short* mb[4];
#pragma unroll
  for (int g = 0; g < 4; ++g) {
    qrow[g] = q0 + g * 64 + wave * 16 + lrow;
    const unsigned short* qp = Qm + base + (size_t)qrow[g] * EHD + lgrp * 8;
    qf0[g] = *(const bf16x8*)qp;
    qf1[g] = *(const bf16x8*)(qp + 32);
    mb[g] = Mb + (size_t)qrow[g] * T_DIM + lgrp * 4;
  }

  f32x4 oacc[4][4];
#pragma unroll
  for (int g = 0; g < 4; ++g)
#pragma unroll
    for (int n = 0; n < 4; ++n) oacc[g][n] = (f32x4){0.f, 0.f, 0.f, 0.f};
  f32x2 racc[4];
#pragma unroll
  for (int g = 0; g < 4; ++g) racc[g] = (f32x2){0.f, 0.f};

  const int rr = lane >> 3;
  const int cs = (((lane & 7) ^ rr) * 8);
  const int r0w = wave * 8;
  const int rx = (lrow & 7) * 8;
  const int c0 = (lgrp * 8) ^ rx;

#define STAGE(bufi, kv0)                                                        \
  {                                                                             \
    _Pragma("unroll") for (int i = 0; i < 2; ++i) {                             \
      const int r0 = i * 32 + r0w;                                              \
      gload16(Km + base + (size_t)((kv0) + r0 + rr) * EHD + cs,                 \
              &Ks[bufi][r0 * 64]);                                              \
      gload16(Vtm + base + (size_t)(kv0) * EHD + (r0 + rr) * 64 + cs,           \
              &Vs[bufi][r0 * 64]);                                              \
    }                                                                           \
  }

  short* plw[4];
#pragma unroll
  for (int g = 0; g < 4; ++g) plw[g] = &Pl[wave][g][lrow * 64];

  uint2 mreg[2][4][4];  // [tile parity][group][n]: 4 bf16 mask vals packed

#define ATTN_ITER(CUR, DO_PRE, TN)                                              \
  {                                                                             \
    if (DO_PRE) {                                                               \
      STAGE((CUR) ^ 1, (TN) * 64);                                              \
      __builtin_amdgcn_sched_barrier(0);                                        \
      _Pragma("unroll") for (int g = 0; g < 4; ++g) {                           \
        _Pragma("unroll") for (int n = 0; n < 4; ++n) {                         \
          mreg[(CUR) ^ 1][g][n] =                                               \
              *(const uint2*)(mb[g] + (TN) * 64 + n * 16);                      \
        }                                                                       \
      }                                                                         \
    }                                                                           \
    const short* kb = Ks[CUR];                                                  \
    const short* vb = Vs[CUR];                                                  \
    bf16x8 kf[4][2]; /* K fragments once, shared by all 4 groups */             \
    _Pragma("unroll") for (int n = 0; n < 4; ++n) {                             \
      const short* kp = kb + (n * 16 + lrow) * 64;                              \
      kf[n][0] = *(const bf16x8*)(kp + c0);                                     \
      kf[n][1] = *(const bf16x8*)(kp + (c0 ^ 32));                              \
    }                                                                           \
    _Pragma("unroll") for (int g = 0; g < 4; ++g) {                             \
      f32x4 s[4];                                                               \
      __builtin_amdgcn_s_setprio(1);                                            \
      _Pragma("unroll") for (int n = 0; n < 4; ++n) {                           \
        s[n] = (f32x4){0.f, 0.f, 0.f, 0.f};                                     \
        s[n] = __builtin_amdgcn_mfma_f32_16x16x32_bf16(kf[n][0], qf0[g], s[n], 0, 0, 0); \
        s[n] = __builtin_amdgcn_mfma_f32_16x16x32_bf16(kf[n][1], qf1[g], s[n], 0, 0, 0); \
      }                                                                         \
      __builtin_amdgcn_s_setprio(0);                                            \
      _Pragma("unroll") for (int n = 0; n < 4; ++n) {                           \
        const uint2 mw = mreg[CUR][g][n];                                       \
        const f32x2 s01 = {s[n][0], s[n][1]};                                   \
        const f32x2 s23 = {s[n][2], s[n][3]};                                   \
        const f32x2 t01 = __builtin_elementwise_fma(                            \
            s01, bfpair(mw.x), (f32x2){-FMAXC, -FMAXC});                        \
        const f32x2 t23 = __builtin_elementwise_fma(                            \
            s23, bfpair(mw.y), (f32x2){-FMAXC, -FMAXC});                        \
        const float p0 = __builtin_amdgcn_exp2f(t01.x);                         \
        const float p1 = __builtin_amdgcn_exp2f(t01.y);                         \
        const float p2 = __builtin_amdgcn_exp2f(t23.x);                         \
        const float p3 = __builtin_amdgcn_exp2f(t23.y);                         \
        racc[g] += (f32x2){p0, p1} + (f32x2){p2, p3};                           \
        uint2 w;                                                                \
        w.x = pkbf2(p0, p1);                                                    \
        w.y = pkbf2(p2, p3);                                                    \
        *(uint2*)(plw[g] + ((n * 16 + lgrp * 4) ^ rx)) = w;                     \
      }                                                                         \
    }                                                                           \
    __builtin_amdgcn_s_setprio(1);                                              \
    _Pragma("unroll") for (int kc = 0; kc < 2; ++kc) {                          \
      const int pc = ((kc * 32) + lgrp * 8) ^ rx;                               \
      bf16x8 pB[4];                                                             \
      _Pragma("unroll") for (int g = 0; g < 4; ++g)                             \
          pB[g] = *(const bf16x8*)(plw[g] + pc);                                \
      _Pragma("unroll") for (int n = 0; n < 4; ++n) {                           \
        const bf16x8 vf = *(const bf16x8*)(vb + (n * 16 + lrow) * 64 + pc);     \
        _Pragma("unroll") for (int g = 0; g < 4; ++g)                           \
            oacc[g][n] = __builtin_amdgcn_mfma_f32_16x16x32_bf16(               \
                vf, pB[g], oacc[g][n], 0, 0, 0);                                \
      }                                                                         \
    }                                                                           \
    __builtin_amdgcn_s_setprio(0);                                              \
  }

// Retire this iter's 4 STAGE DMAs; keep 16 next-tile mask loads in flight.
#define WAITBAR(N)                                                              \
  asm volatile("s_waitcnt vmcnt(" #N ")" ::: "memory");                         \
  __builtin_amdgcn_sched_barrier(0);                                            \
  __builtin_amdgcn_s_barrier();                                                 \
  __builtin_amdgcn_sched_barrier(0);

  // prologue: stage tile 0 (pinned), prefetch its masks, retire stage
  STAGE(0, 0);
  __builtin_amdgcn_sched_barrier(0);
#pragma unroll
  for (int g = 0; g < 4; ++g)
#pragma unroll
    for (int n = 0; n < 4; ++n) mreg[0][g][n] = *(const uint2*)(mb[g] + n * 16);
  WAITBAR(16)

  // t = 0..29: uniform, stage tile t+1 at iter start
  for (int tt = 0; tt < 15; ++tt) {
    ATTN_ITER(0, 1, 2 * tt + 1);
    WAITBAR(16)
    ATTN_ITER(1, 1, 2 * tt + 2);
    WAITBAR(16)
  }
  // t = 30: stages tile 31
  ATTN_ITER(0, 1, 31);
  WAITBAR(16)
  // t = 31: final tile, no prefetch, no barrier
  ATTN_ITER(1, 0, 0);

#undef ATTN_ITER
#undef WAITBAR
#undef STAGE

#pragma unroll
  for (int g = 0; g < 4; ++g) {
    float lr = racc[g].x + racc[g].y;
    lr += __shfl_xor(lr, 16);
    lr += __shfl_xor(lr, 32);
    const float inv = 1.f / lr;
    unsigned short* cp =
        ctx + ((size_t)b * T_DIM + qrow[g]) * E_DIM + h * EHD + lgrp * 4;
#pragma unroll
    for (int n = 0; n < 4; ++n) {
      uint2 w;
      w.x = pkbf2(oacc[g][n][0] * inv, oacc[g][n][1] * inv);
      w.y = pkbf2(oacc[g][n][2] * inv, oacc[g][n][3] * inv);
      *(uint2*)(cp + n * 16) = w;
    }
  }
}

extern "C" void kernel_launch(void* const* d_in, const int* in_sizes, int n_in,
                              void* d_out, int out_size, void* d_ws, size_t ws_size,
                              hipStream_t stream) {
  const float* q    = (const float*)d_in[0];
  const float* k    = (const float*)d_in[1];
  const float* v    = (const float*)d_in[2];
  const float* mask = (const float*)d_in[3];
  const float* wqkv = (const float*)d_in[4];
  const float* bqkv = (const float*)d_in[5];
  const float* wout = (const float*)d_in[6];
  const float* bout = (const float*)d_in[7];

  char* ws = (char*)d_ws;
  unsigned short* Xb   = (unsigned short*)(ws);
  unsigned short* Wqb  = (unsigned short*)(ws + 50331648);
  unsigned short* Wob  = (unsigned short*)(ws + 56623104);
  unsigned short* QKVb = (unsigned short*)(ws + 58720256);  // [Q|K|Vt] bf16
  unsigned short* CTXb = (unsigned short*)(ws);             // [B][T][E] (Xb dead)
  unsigned short* Mb   = (unsigned short*)(ws + 16777216);  // bf16 mask, in dead Xb

  cvt_kernel<<<2048, 256, 0, stream>>>((const float4*)q, (uint2*)Xb, 2097152);
  cvt_kernel<<<2048, 256, 0, stream>>>((const float4*)k, (uint2*)(Xb + 8388608), 2097152);
  cvt_kernel<<<2048, 256, 0, stream>>>((const float4*)v, (uint2*)(Xb + 16777216), 2097152);
  cvt_kernel<<<1024, 256, 0, stream>>>((const float4*)wqkv, (uint2*)Wqb, 786432);
  cvt_kernel<<<512, 256, 0, stream>>>((const float4*)wout, (uint2*)Wob, 262144);

  gemm_kernel<0><<<dim3(64, 24), 256, 0, stream>>>(Xb, Wqb, bqkv, QKVb, 1024);
  // mask -> bf16 AFTER GEMM1 (Mb lives in the then-dead Xb region)
  cvt_kernel<<<1024, 256, 0, stream>>>((const float4*)mask, (uint2*)Mb, 1048576);
  attn_kernel<<<dim3(8, 64), 256, 0, stream>>>(QKVb, QKVb + 8388608,
                                               QKVb + 16777216, Mb, CTXb);
  gemm_kernel<1><<<dim3(64, 8), 256, 0, stream>>>(CTXb, Wob, bout, d_out, 1024);
}

// Round 16
// 283.808 us; speedup vs baseline: 1.5609x; 1.2671x over previous
//
#include <hip/hip_runtime.h>
#include <hip/hip_bf16.h>
#include <stdint.h>

#define T_DIM 2048
#define B_DIM 4
#define E_DIM 1024
#define H_DIM 16
#define EHD 64
#define L2E 1.4426950408889634f
#define QSCALE (0.125f * L2E)
#define FMAXC 12.0f

typedef __attribute__((ext_vector_type(8))) short bf16x8;
typedef __attribute__((ext_vector_type(4))) float f32x4;
typedef __attribute__((ext_vector_type(2))) float f32x2;
typedef __attribute__((ext_vector_type(2))) unsigned u32x2;

__device__ __forceinline__ unsigned short f2bf(float x) {
  unsigned int u = __builtin_bit_cast(unsigned int, x);
  u += 0x7fffu + ((u >> 16) & 1u);
  return (unsigned short)(u >> 16);
}

__device__ __forceinline__ unsigned pkbf(float a, float b) {
  return (unsigned)f2bf(a) | ((unsigned)f2bf(b) << 16);
}

// fast half-up pack (attn hot loop only): 5 ops/pair, bias < 2^-10 rel.
__device__ __forceinline__ unsigned pkbf2(float a, float b) {
  unsigned ua = __builtin_bit_cast(unsigned, a) + 0x8000u;
  unsigned ub = __builtin_bit_cast(unsigned, b) + 0x8000u;
  return (ua >> 16) | (ub & 0xffff0000u);
}

__device__ __forceinline__ f32x2 bfpair(unsigned w) {
  u32x2 u = {w << 16, w & 0xffff0000u};
  return __builtin_bit_cast(f32x2, u);
}

__device__ __forceinline__ void gload16(const void* g, void* l) {
  __builtin_amdgcn_global_load_lds(
      (const __attribute__((address_space(1))) void*)g,
      (__attribute__((address_space(3))) void*)l, 16, 0, 0);
}

// ---------------- fp32 -> bf16 ----------------
__global__ __launch_bounds__(256) void cvt_kernel(const float4* __restrict__ in,
                                                  uint2* __restrict__ out, int n4) {
  int i = blockIdx.x * 256 + threadIdx.x;
  int stride = gridDim.x * 256;
  for (; i < n4; i += stride) {
    float4 f = in[i];
    uint2 o;
    o.x = pkbf(f.x, f.y);
    o.y = pkbf(f.z, f.w);
    out[i] = o;
  }
}

// ---------------- 128x128 bf16 NT GEMM (m97 structure, round-12 exact) ------
template <int MODE>
__global__ __launch_bounds__(256) void gemm_kernel(
    const unsigned short* __restrict__ Abase,
    const unsigned short* __restrict__ Bt,
    const float* __restrict__ bias,
    void* __restrict__ outv, int K) {
  __shared__ alignas(16) short As[128 * 32];
  __shared__ alignas(16) short Bs[128 * 32];
  const int tid = threadIdx.x;
  const int lane = tid & 63, wave = tid >> 6;
  const int m0 = blockIdx.x * 128, n0 = blockIdx.y * 128;
  const int wr = wave >> 1, wc = wave & 1;
  const int lrow = lane & 15, lgrp = lane >> 4;

  const unsigned short* A = Abase;
  if (MODE == 0) A += (size_t)(n0 >> 10) * (8192u * 1024u);

  f32x4 acc[4][4];
#pragma unroll
  for (int m = 0; m < 4; ++m)
#pragma unroll
    for (int n = 0; n < 4; ++n) acc[m][n] = (f32x4){0.f, 0.f, 0.f, 0.f};

  const int srow = wave * 16 + (lane >> 2);
  const int scol = (lane & 3) * 8;
  short* lA0 = As + wave * 16 * 32;
  short* lA1 = As + (64 + wave * 16) * 32;
  short* lB0 = Bs + wave * 16 * 32;
  short* lB1 = Bs + (64 + wave * 16) * 32;

  for (int k0 = 0; k0 < K; k0 += 32) {
    const unsigned short* ga = A + (size_t)(m0 + srow) * K + k0 + scol;
    const unsigned short* gb = Bt + (size_t)(n0 + srow) * K + k0 + scol;
    gload16(ga, lA0);
    gload16(ga + (size_t)64 * K, lA1);
    gload16(gb, lB0);
    gload16(gb + (size_t)64 * K, lB1);
    __syncthreads();
    const short* pa = As + (wr * 64 + lrow) * 32 + lgrp * 8;
    const short* pb = Bs + (wc * 64 + lrow) * 32 + lgrp * 8;
    bf16x8 a[4], b[4];
#pragma unroll
    for (int m = 0; m < 4; ++m) a[m] = *(const bf16x8*)(pa + m * 512);
#pragma unroll
    for (int n = 0; n < 4; ++n) b[n] = *(const bf16x8*)(pb + n * 512);
#pragma unroll
    for (int m = 0; m < 4; ++m)
#pragma unroll
      for (int n = 0; n < 4; ++n)
        acc[m][n] = __builtin_amdgcn_mfma_f32_16x16x32_bf16(a[m], b[n], acc[m][n], 0, 0, 0);
    __syncthreads();
  }

#pragma unroll
  for (int n = 0; n < 4; ++n) {
    const int gn = n0 + wc * 64 + n * 16 + lrow;
    const float bv = bias[gn];
    if (MODE == 0) {
      unsigned short* out = (unsigned short*)outv;
      const int which = gn >> 10;
      const float qsc = (which == 0) ? QSCALE : 1.0f;
      const int e = gn & 1023;
      const int hh = e >> 6, dd = e & 63;
#pragma unroll
      for (int m = 0; m < 4; ++m)
#pragma unroll
        for (int r = 0; r < 4; ++r) {
          const int gm = m0 + wr * 64 + m * 16 + lgrp * 4 + r;
          const int t = gm >> 2, bb = gm & 3;  // A row index is t*B + b
          const unsigned short val = f2bf((acc[m][n][r] + bv) * qsc);
          if (which == 2) {
            out[((size_t)(2 * B_DIM * H_DIM) + bb * H_DIM + hh) * (T_DIM * EHD) +
                (size_t)(t >> 6) * 4096 + dd * 64 + (t & 63)] = val;
          } else {
            out[((size_t)which * B_DIM * H_DIM + bb * H_DIM + hh) * (T_DIM * EHD) +
                (size_t)t * EHD + dd] = val;
          }
        }
    } else {
      float* out = (float*)outv;
#pragma unroll
      for (int m = 0; m < 4; ++m)
#pragma unroll
        for (int r = 0; r < 4; ++r) {
          const int gm = m0 + wr * 64 + m * 16 + lgrp * 4 + r;  // row = b*T + t
          const int bb = gm >> 11, t = gm & 2047;
          out[((size_t)t * B_DIM + bb) * E_DIM + gn] = acc[m][n][r] + bv;
        }
    }
  }
}

// ---------------- flash attention: LDS-staged mask (TA-transaction fix) -----
// grid (T/128, B*H), 4 waves, 2 q-groups/wave (q=lrow). Fixed-max softmax.
// Round-16 theory: the wall is per-CU VMEM transaction (TA) rate. The mask
// REGISTER gathers were 16 instr x 16 lines = 256 lines/wave-iter (q-rows are
// 4KB-strided), dwarfing K/V DMA's 64. Fix: stage the mask tile [128q][64k]
// bf16 through LDS via global_load_lds (wave-contiguous rows -> 64 lines),
// double-buffered, same G21 XOR involution as K (granule16 ^= row&7).
// Softmax reads mask as 8x ds_read_b64/iter at <=2-way conflict.
// All 8 DMAs issue at iter start -> vmcnt(0)+barrier at iter end is free.
__global__ __launch_bounds__(256, 2) void attn_kernel(
    const unsigned short* __restrict__ Qm, const unsigned short* __restrict__ Km,
    const unsigned short* __restrict__ Vtm, const unsigned short* __restrict__ Mb,
    unsigned short* __restrict__ ctx) {
  __shared__ alignas(16) short Ks[2][4096];
  __shared__ alignas(16) short Vs[2][4096];
  __shared__ alignas(16) short Ml[2][8192];  // [128 q][64 k] bf16, swizzled
  __shared__ alignas(16) short Pl[4][2][1024];
  const int tid = threadIdx.x, lane = tid & 63, wave = tid >> 6;
  const int lrow = lane & 15, lgrp = lane >> 4;
  const int bh = blockIdx.y, b = bh >> 4, h = bh & 15;
  const int q0 = blockIdx.x * 128;

  const size_t base = (size_t)bh * (T_DIM * EHD);

  bf16x8 qf0[2], qf1[2];
  int qrow[2];
#pragma unroll
  for (int g = 0; g < 2; ++g) {
    qrow[g] = q0 + g * 64 + wave * 16 + lrow;
    const unsigned short* qp = Qm + base + (size_t)qrow[g] * EHD + lgrp * 8;
    qf0[g] = *(const bf16x8*)qp;
    qf1[g] = *(const bf16x8*)(qp + 32);
  }

  f32x4 oacc[2][4];
#pragma unroll
  for (int g = 0; g < 2; ++g)
#pragma unroll
    for (int n = 0; n < 4; ++n) oacc[g][n] = (f32x4){0.f, 0.f, 0.f, 0.f};
  f32x2 racc[2] = {(f32x2){0.f, 0.f}, (f32x2){0.f, 0.f}};

  const int rr = lane >> 3;
  const int cs = (((lane & 7) ^ rr) * 8);  // inverse-swizzled source granule
  const int r0w = wave * 8;
  const int rx = (lrow & 7) * 8;
  const int c0 = (lgrp * 8) ^ rx;

// K/V (4 DMAs) + mask (4 DMAs, wave stages q-rows [wave*32, wave*32+32))
#define STAGE(bufi, kv0)                                                        \
  {                                                                             \
    _Pragma("unroll") for (int i = 0; i < 2; ++i) {                             \
      const int r0 = i * 32 + r0w;                                              \
      gload16(Km + base + (size_t)((kv0) + r0 + rr) * EHD + cs,                 \
              &Ks[bufi][r0 * 64]);                                              \
      gload16(Vtm + base + (size_t)(kv0) * EHD + (r0 + rr) * 64 + cs,           \
              &Vs[bufi][r0 * 64]);                                              \
    }                                                                           \
    _Pragma("unroll") for (int i = 0; i < 4; ++i) {                             \
      const int mrow = wave * 32 + i * 8;                                       \
      gload16(Mb + (size_t)(q0 + mrow + rr) * T_DIM + (kv0) + cs,               \
              &Ml[bufi][mrow * 64]);                                            \
    }                                                                           \
  }

  short* plw0 = &Pl[wave][0][lrow * 64];
  short* plw1 = &Pl[wave][1][lrow * 64];
  // mask read bases: row = g*64 + wave*16 + lrow; row&7 == lrow&7
  const int mrb0 = (wave * 16 + lrow) * 64;
  const int mrb1 = (64 + wave * 16 + lrow) * 64;
  const int msub = (lgrp & 1) * 4;  // shorts within 16B granule
  const int mg0 = (lgrp >> 1);      // granule contribution from lgrp

#define ATTN_ITER(CUR, DO_PRE, TN)                                              \
  {                                                                             \
    if (DO_PRE) {                                                               \
      STAGE((CUR) ^ 1, (TN) * 64);                                              \
      __builtin_amdgcn_sched_barrier(0);                                        \
    }                                                                           \
    const short* kb = Ks[CUR];                                                  \
    const short* vb = Vs[CUR];                                                  \
    const short* mlb = Ml[CUR];                                                 \
    float sv[2][4][4];                                                          \
    __builtin_amdgcn_s_setprio(1);                                              \
    _Pragma("unroll") for (int n = 0; n < 4; ++n) {                             \
      const short* kp = kb + (n * 16 + lrow) * 64;                              \
      const bf16x8 kf0 = *(const bf16x8*)(kp + c0);                             \
      const bf16x8 kf1 = *(const bf16x8*)(kp + (c0 ^ 32));                      \
      f32x4 s0 = (f32x4){0.f, 0.f, 0.f, 0.f}, s1 = s0;                          \
      s0 = __builtin_amdgcn_mfma_f32_16x16x32_bf16(kf0, qf0[0], s0, 0, 0, 0);   \
      s0 = __builtin_amdgcn_mfma_f32_16x16x32_bf16(kf1, qf1[0], s0, 0, 0, 0);   \
      s1 = __builtin_amdgcn_mfma_f32_16x16x32_bf16(kf0, qf0[1], s1, 0, 0, 0);   \
      s1 = __builtin_amdgcn_mfma_f32_16x16x32_bf16(kf1, qf1[1], s1, 0, 0, 0);   \
      _Pragma("unroll") for (int r = 0; r < 4; ++r) {                           \
        sv[0][n][r] = s0[r];                                                    \
        sv[1][n][r] = s1[r];                                                    \
      }                                                                         \
    }                                                                           \
    __builtin_amdgcn_s_setprio(0);                                              \
    _Pragma("unroll") for (int g = 0; g < 2; ++g) {                             \
      short* plw = g ? plw1 : plw0;                                             \
      const int mrb = g ? mrb1 : mrb0;                                          \
      _Pragma("unroll") for (int n = 0; n < 4; ++n) {                           \
        const int mgr = (n * 2 + mg0) ^ (lrow & 7);                             \
        const uint2 mw = *(const uint2*)(mlb + mrb + mgr * 8 + msub);           \
        const f32x2 s01 = {sv[g][n][0], sv[g][n][1]};                           \
        const f32x2 s23 = {sv[g][n][2], sv[g][n][3]};                           \
        const f32x2 t01 = __builtin_elementwise_fma(                            \
            s01, bfpair(mw.x), (f32x2){-FMAXC, -FMAXC});                        \
        const f32x2 t23 = __builtin_elementwise_fma(                            \
            s23, bfpair(mw.y), (f32x2){-FMAXC, -FMAXC});                        \
        const float p0 = __builtin_amdgcn_exp2f(t01.x);                         \
        const float p1 = __builtin_amdgcn_exp2f(t01.y);                         \
        const float p2 = __builtin_amdgcn_exp2f(t23.x);                         \
        const float p3 = __builtin_amdgcn_exp2f(t23.y);                         \
        racc[g] += (f32x2){p0, p1} + (f32x2){p2, p3};                           \
        uint2 w;                                                                \
        w.x = pkbf2(p0, p1);                                                    \
        w.y = pkbf2(p2, p3);                                                    \
        *(uint2*)(plw + ((n * 16 + lgrp * 4) ^ rx)) = w;                        \
      }                                                                         \
    }                                                                           \
    __builtin_amdgcn_s_setprio(1);                                              \
    _Pragma("unroll") for (int kc = 0; kc < 2; ++kc) {                          \
      const int pc = ((kc * 32) + lgrp * 8) ^ rx;                               \
      const bf16x8 pB0 = *(const bf16x8*)(plw0 + pc);                           \
      const bf16x8 pB1 = *(const bf16x8*)(plw1 + pc);                           \
      _Pragma("unroll") for (int n = 0; n < 4; ++n) {                           \
        const bf16x8 vf = *(const bf16x8*)(vb + (n * 16 + lrow) * 64 + pc);     \
        oacc[0][n] = __builtin_amdgcn_mfma_f32_16x16x32_bf16(vf, pB0, oacc[0][n], 0, 0, 0); \
        oacc[1][n] = __builtin_amdgcn_mfma_f32_16x16x32_bf16(vf, pB1, oacc[1][n], 0, 0, 0); \
      }                                                                         \
    }                                                                           \
    __builtin_amdgcn_s_setprio(0);                                              \
  }

// All 8 DMAs were issued at iter start (~full iter before this wait).
#define WAITBAR                                                                 \
  asm volatile("s_waitcnt vmcnt(0)" ::: "memory");                              \
  __builtin_amdgcn_sched_barrier(0);                                            \
  __builtin_amdgcn_s_barrier();                                                 \
  __builtin_amdgcn_sched_barrier(0);

  // prologue: stage tile 0, retire, barrier
  STAGE(0, 0);
  WAITBAR

  // t = 0..29: uniform, stage tile t+1 at iter start
  for (int tt = 0; tt < 15; ++tt) {
    ATTN_ITER(0, 1, 2 * tt + 1);
    WAITBAR
    ATTN_ITER(1, 1, 2 * tt + 2);
    WAITBAR
  }
  // t = 30: stages tile 31
  ATTN_ITER(0, 1, 31);
  WAITBAR
  // t = 31: final tile, no prefetch, no barrier
  ATTN_ITER(1, 0, 0);

#undef ATTN_ITER
#undef WAITBAR
#undef STAGE

#pragma unroll
  for (int g = 0; g < 2; ++g) {
    float lr = racc[g].x + racc[g].y;
    lr += __shfl_xor(lr, 16);
    lr += __shfl_xor(lr, 32);
    const float inv = 1.f / lr;
    unsigned short* cp =
        ctx + ((size_t)b * T_DIM + qrow[g]) * E_DIM + h * EHD + lgrp * 4;
#pragma unroll
    for (int n = 0; n < 4; ++n) {
      uint2 w;
      w.x = pkbf2(oacc[g][n][0] * inv, oacc[g][n][1] * inv);
      w.y = pkbf2(oacc[g][n][2] * inv, oacc[g][n][3] * inv);
      *(uint2*)(cp + n * 16) = w;
    }
  }
}

extern "C" void kernel_launch(void* const* d_in, const int* in_sizes, int n_in,
                              void* d_out, int out_size, void* d_ws, size_t ws_size,
                              hipStream_t stream) {
  const float* q    = (const float*)d_in[0];
  const float* k    = (const float*)d_in[1];
  const float* v    = (const float*)d_in[2];
  const float* mask = (const float*)d_in[3];
  const float* wqkv = (const float*)d_in[4];
  const float* bqkv = (const float*)d_in[5];
  const float* wout = (const float*)d_in[6];
  const float* bout = (const float*)d_in[7];

  char* ws = (char*)d_ws;
  unsigned short* Xb   = (unsigned short*)(ws);
  unsigned short* Wqb  = (unsigned short*)(ws + 50331648);
  unsigned short* Wob  = (unsigned short*)(ws + 56623104);
  unsigned short* QKVb = (unsigned short*)(ws + 58720256);  // [Q|K|Vt] bf16
  unsigned short* CTXb = (unsigned short*)(ws);             // [B][T][E] (Xb dead)
  unsigned short* Mb   = (unsigned short*)(ws + 16777216);  // bf16 mask, in dead Xb

  cvt_kernel<<<2048, 256, 0, stream>>>((const float4*)q, (uint2*)Xb, 2097152);
  cvt_kernel<<<2048, 256, 0, stream>>>((const float4*)k, (uint2*)(Xb + 8388608), 2097152);
  cvt_kernel<<<2048, 256, 0, stream>>>((const float4*)v, (uint2*)(Xb + 16777216), 2097152);
  cvt_kernel<<<1024, 256, 0, stream>>>((const float4*)wqkv, (uint2*)Wqb, 786432);
  cvt_kernel<<<512, 256, 0, stream>>>((const float4*)wout, (uint2*)Wob, 262144);

  gemm_kernel<0><<<dim3(64, 24), 256, 0, stream>>>(Xb, Wqb, bqkv, QKVb, 1024);
  // mask -> bf16 AFTER GEMM1 (Mb lives in the then-dead Xb region)
  cvt_kernel<<<1024, 256, 0, stream>>>((const float4*)mask, (uint2*)Mb, 1048576);
  attn_kernel<<<dim3(16, 64), 256, 0, stream>>>(QKVb, QKVb + 8388608,
                                                QKVb + 16777216, Mb, CTXb);
  gemm_kernel<1><<<dim3(64, 8), 256, 0, stream>>>(CTXb, Wob, bout, d_out, 1024);
}

// Round 17
// 269.320 us; speedup vs baseline: 1.6449x; 1.0538x over previous
//
#include <hip/hip_runtime.h>
#include <hip/hip_bf16.h>
#include <stdint.h>

#define T_DIM 2048
#define B_DIM 4
#define E_DIM 1024
#define H_DIM 16
#define EHD 64
#define L2E 1.4426950408889634f
#define QSCALE (0.125f * L2E)
#define FMAXC 12.0f

typedef __attribute__((ext_vector_type(8))) short bf16x8;
typedef __attribute__((ext_vector_type(4))) float f32x4;
typedef __attribute__((ext_vector_type(2))) float f32x2;
typedef __attribute__((ext_vector_type(2))) unsigned u32x2;

__device__ __forceinline__ unsigned short f2bf(float x) {
  unsigned int u = __builtin_bit_cast(unsigned int, x);
  u += 0x7fffu + ((u >> 16) & 1u);
  return (unsigned short)(u >> 16);
}

__device__ __forceinline__ unsigned pkbf(float a, float b) {
  return (unsigned)f2bf(a) | ((unsigned)f2bf(b) << 16);
}

// truncation pack (P hot path only): ~3 VALU (or 1 v_perm). Bias <=0.4%
// cancels in O = sum(pV)/sum(p). RNE kept for inputs/mask/epilogue.
__device__ __forceinline__ unsigned pk_trunc(float a, float b) {
  return (__builtin_bit_cast(unsigned, a) >> 16) |
         (__builtin_bit_cast(unsigned, b) & 0xffff0000u);
}

__device__ __forceinline__ f32x2 bfpair(unsigned lo, unsigned hi_w) {
  u32x2 u = {lo << 16, hi_w & 0xffff0000u};
  return __builtin_bit_cast(f32x2, u);
}

__device__ __forceinline__ void gload16(const void* g, void* l) {
  __builtin_amdgcn_global_load_lds(
      (const __attribute__((address_space(1))) void*)g,
      (__attribute__((address_space(3))) void*)l, 16, 0, 0);
}

// ---------------- fused fp32 -> bf16 for all 5 inputs (1 launch) ------------
__global__ __launch_bounds__(256) void cvt_fused(
    const float4* __restrict__ q, const float4* __restrict__ k,
    const float4* __restrict__ v, const float4* __restrict__ wqkv,
    const float4* __restrict__ wout, uint2* __restrict__ xq,
    uint2* __restrict__ xk, uint2* __restrict__ xv, uint2* __restrict__ wq,
    uint2* __restrict__ wo) {
  int i = blockIdx.x * 256 + threadIdx.x;
  const int stride = gridDim.x * 256;
  for (; i < 7340032; i += stride) {
    const float4* s;
    uint2* d;
    int j;
    if (i < 2097152) { s = q; d = xq; j = i; }
    else if (i < 4194304) { s = k; d = xk; j = i - 2097152; }
    else if (i < 6291456) { s = v; d = xv; j = i - 4194304; }
    else if (i < 7077888) { s = wqkv; d = wq; j = i - 6291456; }
    else { s = wout; d = wo; j = i - 7077888; }
    const float4 f = s[j];
    uint2 o;
    o.x = pkbf(f.x, f.y);
    o.y = pkbf(f.z, f.w);
    d[j] = o;
  }
}

// ---------------- mask fp32 -> bf16, PERMUTED to lane-contiguous 32B --------
// out[c], c = ((((qblk*32+t)*2+h)*4+wave)*2+g)*64+lane : 16B holding mask
// values for (q = qblk*128+g*64+wave*16+lrow, k = t*64+(h*2..h*2+1)*16+lgrp*4+r)
// -> attn softmax reads its 16 values as 2 contiguous ds_read_b128.
__global__ __launch_bounds__(256) void mask_perm(const float* __restrict__ mask,
                                                 uint4* __restrict__ out) {
  const int c = blockIdx.x * 256 + threadIdx.x;  // grid 2048*256 = 524288 exact
  const int lane = c & 63;
  const int g = (c >> 6) & 1;
  const int wave = (c >> 7) & 3;
  const int h = (c >> 9) & 1;
  const int t = (c >> 10) & 31;
  const int qblk = c >> 15;
  const int lrow = lane & 15, lgrp = lane >> 4;
  const int qq = qblk * 128 + g * 64 + wave * 16 + lrow;
  const int k0 = t * 64 + h * 32 + lgrp * 4;
  const float4 f0 = *(const float4*)(mask + (size_t)qq * T_DIM + k0);
  const float4 f1 = *(const float4*)(mask + (size_t)qq * T_DIM + k0 + 16);
  uint4 o;
  o.x = pkbf(f0.x, f0.y);
  o.y = pkbf(f0.z, f0.w);
  o.z = pkbf(f1.x, f1.y);
  o.w = pkbf(f1.z, f1.w);
  out[c] = o;
}

// ---------------- 128x128 bf16 NT GEMM (m97 structure, round-12 exact) ------
template <int MODE>
__global__ __launch_bounds__(256) void gemm_kernel(
    const unsigned short* __restrict__ Abase,
    const unsigned short* __restrict__ Bt,
    const float* __restrict__ bias,
    void* __restrict__ outv, int K) {
  __shared__ alignas(16) short As[128 * 32];
  __shared__ alignas(16) short Bs[128 * 32];
  const int tid = threadIdx.x;
  const int lane = tid & 63, wave = tid >> 6;
  const int m0 = blockIdx.x * 128, n0 = blockIdx.y * 128;
  const int wr = wave >> 1, wc = wave & 1;
  const int lrow = lane & 15, lgrp = lane >> 4;

  const unsigned short* A = Abase;
  if (MODE == 0) A += (size_t)(n0 >> 10) * (8192u * 1024u);

  f32x4 acc[4][4];
#pragma unroll
  for (int m = 0; m < 4; ++m)
#pragma unroll
    for (int n = 0; n < 4; ++n) acc[m][n] = (f32x4){0.f, 0.f, 0.f, 0.f};

  const int srow = wave * 16 + (lane >> 2);
  const int scol = (lane & 3) * 8;
  short* lA0 = As + wave * 16 * 32;
  short* lA1 = As + (64 + wave * 16) * 32;
  short* lB0 = Bs + wave * 16 * 32;
  short* lB1 = Bs + (64 + wave * 16) * 32;

  for (int k0 = 0; k0 < K; k0 += 32) {
    const unsigned short* ga = A + (size_t)(m0 + srow) * K + k0 + scol;
    const unsigned short* gb = Bt + (size_t)(n0 + srow) * K + k0 + scol;
    gload16(ga, lA0);
    gload16(ga + (size_t)64 * K, lA1);
    gload16(gb, lB0);
    gload16(gb + (size_t)64 * K, lB1);
    __syncthreads();
    const short* pa = As + (wr * 64 + lrow) * 32 + lgrp * 8;
    const short* pb = Bs + (wc * 64 + lrow) * 32 + lgrp * 8;
    bf16x8 a[4], b[4];
#pragma unroll
    for (int m = 0; m < 4; ++m) a[m] = *(const bf16x8*)(pa + m * 512);
#pragma unroll
    for (int n = 0; n < 4; ++n) b[n] = *(const bf16x8*)(pb + n * 512);
#pragma unroll
    for (int m = 0; m < 4; ++m)
#pragma unroll
      for (int n = 0; n < 4; ++n)
        acc[m][n] = __builtin_amdgcn_mfma_f32_16x16x32_bf16(a[m], b[n], acc[m][n], 0, 0, 0);
    __syncthreads();
  }

#pragma unroll
  for (int n = 0; n < 4; ++n) {
    const int gn = n0 + wc * 64 + n * 16 + lrow;
    const float bv = bias[gn];
    if (MODE == 0) {
      unsigned short* out = (unsigned short*)outv;
      const int which = gn >> 10;
      const float qsc = (which == 0) ? QSCALE : 1.0f;
      const int e = gn & 1023;
      const int hh = e >> 6, dd = e & 63;
#pragma unroll
      for (int m = 0; m < 4; ++m)
#pragma unroll
        for (int r = 0; r < 4; ++r) {
          const int gm = m0 + wr * 64 + m * 16 + lgrp * 4 + r;
          const int t = gm >> 2, bb = gm & 3;  // A row index is t*B + b
          const unsigned short val = f2bf((acc[m][n][r] + bv) * qsc);
          if (which == 2) {
            out[((size_t)(2 * B_DIM * H_DIM) + bb * H_DIM + hh) * (T_DIM * EHD) +
                (size_t)(t >> 6) * 4096 + dd * 64 + (t & 63)] = val;
          } else {
            out[((size_t)which * B_DIM * H_DIM + bb * H_DIM + hh) * (T_DIM * EHD) +
                (size_t)t * EHD + dd] = val;
          }
        }
    } else {
      float* out = (float*)outv;
#pragma unroll
      for (int m = 0; m < 4; ++m)
#pragma unroll
        for (int r = 0; r < 4; ++r) {
          const int gm = m0 + wr * 64 + m * 16 + lgrp * 4 + r;  // row = b*T + t
          const int bb = gm >> 11, t = gm & 2047;
          out[((size_t)t * B_DIM + bb) * E_DIM + gn] = acc[m][n][r] + bv;
        }
    }
  }
}

// ---------------- flash attention: LDS mask (permuted) + trunc pack ---------
// grid (T/128, B*H), 4 waves, 2 q-groups/wave (q=lrow). Fixed-max softmax.
// Round 17: DS diet. Mask pre-permuted in global (mask_perm) so each lane's
// 16 values are contiguous 32B -> 2x ds_read_b128 per g (conflict-free,
// was 8x 4-way b64). P pack via truncation (3 ops vs 5). K/V staging and
// schedule identical to round 16 (vmcnt(0)+barrier, all DMAs at iter start).
__global__ __launch_bounds__(256, 2) void attn_kernel(
    const unsigned short* __restrict__ Qm, const unsigned short* __restrict__ Km,
    const unsigned short* __restrict__ Vtm, const unsigned short* __restrict__ Mb,
    unsigned short* __restrict__ ctx) {
  __shared__ alignas(16) short Ks[2][4096];
  __shared__ alignas(16) short Vs[2][4096];
  __shared__ alignas(16) short Ml[2][8192];  // 16 slices of [64 lanes][16B]
  __shared__ alignas(16) short Pl[4][2][1024];
  const int tid = threadIdx.x, lane = tid & 63, wave = tid >> 6;
  const int lrow = lane & 15, lgrp = lane >> 4;
  const int bh = blockIdx.y, b = bh >> 4, h = bh & 15;
  const int q0 = blockIdx.x * 128;

  const size_t base = (size_t)bh * (T_DIM * EHD);
  const unsigned short* mbase = Mb + (size_t)blockIdx.x * 262144;  // qblk*32*8192

  bf16x8 qf0[2], qf1[2];
  int qrow[2];
#pragma unroll
  for (int g = 0; g < 2; ++g) {
    qrow[g] = q0 + g * 64 + wave * 16 + lrow;
    const unsigned short* qp = Qm + base + (size_t)qrow[g] * EHD + lgrp * 8;
    qf0[g] = *(const bf16x8*)qp;
    qf1[g] = *(const bf16x8*)(qp + 32);
  }

  f32x4 oacc[2][4];
#pragma unroll
  for (int g = 0; g < 2; ++g)
#pragma unroll
    for (int n = 0; n < 4; ++n) oacc[g][n] = (f32x4){0.f, 0.f, 0.f, 0.f};
  f32x2 racc[2] = {(f32x2){0.f, 0.f}, (f32x2){0.f, 0.f}};

  const int rr = lane >> 3;
  const int cs = (((lane & 7) ^ rr) * 8);  // K/V inverse-swizzled source
  const int r0w = wave * 8;
  const int rx = (lrow & 7) * 8;
  const int c0 = (lgrp * 8) ^ rx;

// K/V (4 DMAs, swizzled) + mask (4 DMAs, linear per-slice)
#define STAGE(bufi, T)                                                          \
  {                                                                             \
    const int kv0 = (T) * 64;                                                   \
    _Pragma("unroll") for (int i = 0; i < 2; ++i) {                             \
      const int r0 = i * 32 + r0w;                                              \
      gload16(Km + base + (size_t)(kv0 + r0 + rr) * EHD + cs,                   \
              &Ks[bufi][r0 * 64]);                                              \
      gload16(Vtm + base + (size_t)kv0 * EHD + (r0 + rr) * 64 + cs,             \
              &Vs[bufi][r0 * 64]);                                              \
    }                                                                           \
    _Pragma("unroll") for (int h2 = 0; h2 < 2; ++h2) {                          \
      _Pragma("unroll") for (int p = 0; p < 2; ++p) {                           \
        const int sl = (h2 * 4 + wave) * 2 + p;                                 \
        gload16(mbase + (size_t)(T) * 8192 + sl * 512 + lane * 8,               \
                &Ml[bufi][sl * 512]);                                           \
      }                                                                         \
    }                                                                           \
  }

  short* plw0 = &Pl[wave][0][lrow * 64];
  short* plw1 = &Pl[wave][1][lrow * 64];

#define ATTN_ITER(CUR, DO_PRE, TN)                                              \
  {                                                                             \
    if (DO_PRE) {                                                               \
      STAGE((CUR) ^ 1, TN);                                                     \
      __builtin_amdgcn_sched_barrier(0);                                        \
    }                                                                           \
    const short* kb = Ks[CUR];                                                  \
    const short* vb = Vs[CUR];                                                  \
    const short* mlb = Ml[CUR];                                                 \
    float sv[2][4][4];                                                          \
    __builtin_amdgcn_s_setprio(1);                                              \
    _Pragma("unroll") for (int n = 0; n < 4; ++n) {                             \
      const short* kp = kb + (n * 16 + lrow) * 64;                              \
      const bf16x8 kf0 = *(const bf16x8*)(kp + c0);                             \
      const bf16x8 kf1 = *(const bf16x8*)(kp + (c0 ^ 32));                      \
      f32x4 s0 = (f32x4){0.f, 0.f, 0.f, 0.f}, s1 = s0;                          \
      s0 = __builtin_amdgcn_mfma_f32_16x16x32_bf16(kf0, qf0[0], s0, 0, 0, 0);   \
      s0 = __builtin_amdgcn_mfma_f32_16x16x32_bf16(kf1, qf1[0], s0, 0, 0, 0);   \
      s1 = __builtin_amdgcn_mfma_f32_16x16x32_bf16(kf0, qf0[1], s1, 0, 0, 0);   \
      s1 = __builtin_amdgcn_mfma_f32_16x16x32_bf16(kf1, qf1[1], s1, 0, 0, 0);   \
      _Pragma("unroll") for (int r = 0; r < 4; ++r) {                           \
        sv[0][n][r] = s0[r];                                                    \
        sv[1][n][r] = s1[r];                                                    \
      }                                                                         \
    }                                                                           \
    __builtin_amdgcn_s_setprio(0);                                              \
    _Pragma("unroll") for (int g = 0; g < 2; ++g) {                             \
      short* plw = g ? plw1 : plw0;                                             \
      const uint4 m01 =                                                         \
          *(const uint4*)(mlb + (wave * 2 + g) * 512 + lane * 8);               \
      const uint4 m23 =                                                         \
          *(const uint4*)(mlb + ((4 + wave) * 2 + g) * 512 + lane * 8);         \
      const unsigned mwx[4] = {m01.x, m01.z, m23.x, m23.z};                     \
      const unsigned mwy[4] = {m01.y, m01.w, m23.y, m23.w};                     \
      _Pragma("unroll") for (int n = 0; n < 4; ++n) {                           \
        const f32x2 s01 = {sv[g][n][0], sv[g][n][1]};                           \
        const f32x2 s23 = {sv[g][n][2], sv[g][n][3]};                           \
        const f32x2 m0v = bfpair(mwx[n], mwx[n]);                               \
        const f32x2 m1v = bfpair(mwy[n], mwy[n]);                               \
        const f32x2 t01 = __builtin_elementwise_fma(                            \
            s01, m0v, (f32x2){-FMAXC, -FMAXC});                                 \
        const f32x2 t23 = __builtin_elementwise_fma(                            \
            s23, m1v, (f32x2){-FMAXC, -FMAXC});                                 \
        const float p0 = __builtin_amdgcn_exp2f(t01.x);                         \
        const float p1 = __builtin_amdgcn_exp2f(t01.y);                         \
        const float p2 = __builtin_amdgcn_exp2f(t23.x);                         \
        const float p3 = __builtin_amdgcn_exp2f(t23.y);                         \
        racc[g] += (f32x2){p0, p1} + (f32x2){p2, p3};                           \
        uint2 w;                                                                \
        w.x = pk_trunc(p0, p1);                                                 \
        w.y = pk_trunc(p2, p3);                                                 \
        *(uint2*)(plw + ((n * 16 + lgrp * 4) ^ rx)) = w;                        \
      }                                                                         \
    }                                                                           \
    __builtin_amdgcn_s_setprio(1);                                              \
    _Pragma("unroll") for (int kc = 0; kc < 2; ++kc) {                          \
      const int pc = ((kc * 32) + lgrp * 8) ^ rx;                               \
      const bf16x8 pB0 = *(const bf16x8*)(plw0 + pc);                           \
      const bf16x8 pB1 = *(const bf16x8*)(plw1 + pc);                           \
      _Pragma("unroll") for (int n = 0; n < 4; ++n) {                           \
        const bf16x8 vf = *(const bf16x8*)(vb + (n * 16 + lrow) * 64 + pc);     \
        oacc[0][n] = __builtin_amdgcn_mfma_f32_16x16x32_bf16(vf, pB0, oacc[0][n], 0, 0, 0); \
        oacc[1][n] = __builtin_amdgcn_mfma_f32_16x16x32_bf16(vf, pB1, oacc[1][n], 0, 0, 0); \
      }                                                                         \
    }                                                                           \
    __builtin_amdgcn_s_setprio(0);                                              \
  }

// All 8 DMAs were issued at iter start (~full iter before this wait).
#define WAITBAR                                                                 \
  asm volatile("s_waitcnt vmcnt(0)" ::: "memory");                              \
  __builtin_amdgcn_sched_barrier(0);                                            \
  __builtin_amdgcn_s_barrier();                                                 \
  __builtin_amdgcn_sched_barrier(0);

  STAGE(0, 0);
  WAITBAR

  for (int tt = 0; tt < 15; ++tt) {
    ATTN_ITER(0, 1, 2 * tt + 1);
    WAITBAR
    ATTN_ITER(1, 1, 2 * tt + 2);
    WAITBAR
  }
  ATTN_ITER(0, 1, 31);
  WAITBAR
  ATTN_ITER(1, 0, 0);

#undef ATTN_ITER
#undef WAITBAR
#undef STAGE

#pragma unroll
  for (int g = 0; g < 2; ++g) {
    float lr = racc[g].x + racc[g].y;
    lr += __shfl_xor(lr, 16);
    lr += __shfl_xor(lr, 32);
    const float inv = 1.f / lr;
    unsigned short* cp =
        ctx + ((size_t)b * T_DIM + qrow[g]) * E_DIM + h * EHD + lgrp * 4;
#pragma unroll
    for (int n = 0; n < 4; ++n) {
      uint2 w;
      w.x = pkbf(oacc[g][n][0] * inv, oacc[g][n][1] * inv);
      w.y = pkbf(oacc[g][n][2] * inv, oacc[g][n][3] * inv);
      *(uint2*)(cp + n * 16) = w;
    }
  }
}

extern "C" void kernel_launch(void* const* d_in, const int* in_sizes, int n_in,
                              void* d_out, int out_size, void* d_ws, size_t ws_size,
                              hipStream_t stream) {
  const float* q    = (const float*)d_in[0];
  const float* k    = (const float*)d_in[1];
  const float* v    = (const float*)d_in[2];
  const float* mask = (const float*)d_in[3];
  const float* wqkv = (const float*)d_in[4];
  const float* bqkv = (const float*)d_in[5];
  const float* wout = (const float*)d_in[6];
  const float* bout = (const float*)d_in[7];

  char* ws = (char*)d_ws;
  unsigned short* Xb   = (unsigned short*)(ws);
  unsigned short* Wqb  = (unsigned short*)(ws + 50331648);
  unsigned short* Wob  = (unsigned short*)(ws + 56623104);
  unsigned short* QKVb = (unsigned short*)(ws + 58720256);  // [Q|K|Vt] bf16
  unsigned short* CTXb = (unsigned short*)(ws);             // [B][T][E] (Xb dead)
  unsigned short* Mb   = (unsigned short*)(ws + 16777216);  // permuted bf16 mask

  cvt_fused<<<2048, 256, 0, stream>>>(
      (const float4*)q, (const float4*)k, (const float4*)v,
      (const float4*)wqkv, (const float4*)wout, (uint2*)Xb,
      (uint2*)(Xb + 8388608), (uint2*)(Xb + 16777216), (uint2*)Wqb,
      (uint2*)Wob);

  gemm_kernel<0><<<dim3(64, 24), 256, 0, stream>>>(Xb, Wqb, bqkv, QKVb, 1024);
  // mask -> permuted bf16 AFTER GEMM1 (Mb lives in the then-dead Xb region)
  mask_perm<<<2048, 256, 0, stream>>>(mask, (uint4*)Mb);
  attn_kernel<<<dim3(16, 64), 256, 0, stream>>>(QKVb, QKVb + 8388608,
                                                QKVb + 16777216, Mb, CTXb);
  gemm_kernel<1><<<dim3(64, 8), 256, 0, stream>>>(CTXb, Wob, bout, d_out, 1024);
}

// Round 18
// 255.277 us; speedup vs baseline: 1.7354x; 1.0550x over previous
//
#include <hip/hip_runtime.h>
#include <hip/hip_bf16.h>
#include <stdint.h>

#define T_DIM 2048
#define B_DIM 4
#define E_DIM 1024
#define H_DIM 16
#define EHD 64
#define L2E 1.4426950408889634f
#define QSCALE (0.125f * L2E)
#define FMAXC 12.0f

typedef __attribute__((ext_vector_type(8))) short bf16x8;
typedef __attribute__((ext_vector_type(4))) float f32x4;
typedef __attribute__((ext_vector_type(16))) float f32x16;
typedef __attribute__((ext_vector_type(2))) float f32x2;
typedef __attribute__((ext_vector_type(2))) unsigned u32x2;
typedef __attribute__((ext_vector_type(4))) unsigned u32x4;

__device__ __forceinline__ unsigned short f2bf(float x) {
  unsigned int u = __builtin_bit_cast(unsigned int, x);
  u += 0x7fffu + ((u >> 16) & 1u);
  return (unsigned short)(u >> 16);
}

__device__ __forceinline__ unsigned pkbf(float a, float b) {
  return (unsigned)f2bf(a) | ((unsigned)f2bf(b) << 16);
}

// truncation pack (P hot path only; bias cancels in sum(pV)/sum(p))
__device__ __forceinline__ unsigned pk_trunc(float a, float b) {
  return (__builtin_bit_cast(unsigned, a) >> 16) |
         (__builtin_bit_cast(unsigned, b) & 0xffff0000u);
}

// expand packed bf16 pair (lo, hi) -> f32x2
__device__ __forceinline__ f32x2 bfpair1(unsigned w) {
  u32x2 u = {w << 16, w & 0xffff0000u};
  return __builtin_bit_cast(f32x2, u);
}

__device__ __forceinline__ void gload16(const void* g, void* l) {
  __builtin_amdgcn_global_load_lds(
      (const __attribute__((address_space(1))) void*)g,
      (__attribute__((address_space(3))) void*)l, 16, 0, 0);
}

// ---------------- fused fp32 -> bf16 for all 5 inputs (1 launch) ------------
__global__ __launch_bounds__(256) void cvt_fused(
    const float4* __restrict__ q, const float4* __restrict__ k,
    const float4* __restrict__ v, const float4* __restrict__ wqkv,
    const float4* __restrict__ wout, uint2* __restrict__ xq,
    uint2* __restrict__ xk, uint2* __restrict__ xv, uint2* __restrict__ wq,
    uint2* __restrict__ wo) {
  int i = blockIdx.x * 256 + threadIdx.x;
  const int stride = gridDim.x * 256;
  for (; i < 7340032; i += stride) {
    const float4* s;
    uint2* d;
    int j;
    if (i < 2097152) { s = q; d = xq; j = i; }
    else if (i < 4194304) { s = k; d = xk; j = i - 2097152; }
    else if (i < 6291456) { s = v; d = xv; j = i - 4194304; }
    else if (i < 7077888) { s = wqkv; d = wq; j = i - 6291456; }
    else { s = wout; d = wo; j = i - 7077888; }
    const float4 f = s[j];
    uint2 o;
    o.x = pkbf(f.x, f.y);
    o.y = pkbf(f.z, f.w);
    d[j] = o;
  }
}

// ---------------- mask fp32 -> bf16, permuted to 32x32 C-fragment order -----
// uint4 index c = ((((qblk*32+t)*4+wave)*2+kb)*2+half)*64+lane.
// Holds mask for q = qblk*128+wave*32+(lane&31),
// k = t*64 + kb*32 + 16*half + 4*(lane>>5) + {0,1,2,3, 8,9,10,11} (rr order).
__global__ __launch_bounds__(256) void mask_perm(const float* __restrict__ mask,
                                                 uint4* __restrict__ out) {
  const int c = blockIdx.x * 256 + threadIdx.x;  // grid 2048*256 = 524288 exact
  const int lane = c & 63;
  const int half = (c >> 6) & 1;
  const int kb = (c >> 7) & 1;
  const int wave = (c >> 8) & 3;
  const int t = (c >> 10) & 31;
  const int qblk = c >> 15;
  const int hi = lane >> 5;
  const int qq = qblk * 128 + wave * 32 + (lane & 31);
  const int kbase = t * 64 + kb * 32 + half * 16 + hi * 4;
  const float4 f0 = *(const float4*)(mask + (size_t)qq * T_DIM + kbase);
  const float4 f1 = *(const float4*)(mask + (size_t)qq * T_DIM + kbase + 8);
  uint4 o;
  o.x = pkbf(f0.x, f0.y);
  o.y = pkbf(f0.z, f0.w);
  o.z = pkbf(f1.x, f1.y);
  o.w = pkbf(f1.z, f1.w);
  out[c] = o;
}

// ---------------- 128x128 bf16 NT GEMM (m97 structure) ----------------
// MODE 0: QKV proj. Q third pre-scaled, row-major [bh][t][d].
//         K third -> fragment-permuted KP[bh][tile][kb*4+i][lane][j]
//           (kb=(t>>5)&1, ql=t&31, i=dd>>4, hi=(dd>>3)&1, j=dd&7, lane=hi*32+ql)
//         V third -> fragment-permuted VP[bh][tile][dblk*4+c][lane][j]
//           (c=(t>>4)&3, hi=(t>>3)&1, j=t&7, dblk=dd>>5, lane=hi*32+(dd&31))
// MODE 1: out projection -> FP32 out[(t*B+b)*E + n].
template <int MODE>
__global__ __launch_bounds__(256) void gemm_kernel(
    const unsigned short* __restrict__ Abase,
    const unsigned short* __restrict__ Bt,
    const float* __restrict__ bias,
    void* __restrict__ outv, int K) {
  __shared__ alignas(16) short As[128 * 32];
  __shared__ alignas(16) short Bs[128 * 32];
  const int tid = threadIdx.x;
  const int lane = tid & 63, wave = tid >> 6;
  const int m0 = blockIdx.x * 128, n0 = blockIdx.y * 128;
  const int wr = wave >> 1, wc = wave & 1;
  const int lrow = lane & 15, lgrp = lane >> 4;

  const unsigned short* A = Abase;
  if (MODE == 0) A += (size_t)(n0 >> 10) * (8192u * 1024u);

  f32x4 acc[4][4];
#pragma unroll
  for (int m = 0; m < 4; ++m)
#pragma unroll
    for (int n = 0; n < 4; ++n) acc[m][n] = (f32x4){0.f, 0.f, 0.f, 0.f};

  const int srow = wave * 16 + (lane >> 2);
  const int scol = (lane & 3) * 8;
  short* lA0 = As + wave * 16 * 32;
  short* lA1 = As + (64 + wave * 16) * 32;
  short* lB0 = Bs + wave * 16 * 32;
  short* lB1 = Bs + (64 + wave * 16) * 32;

  for (int k0 = 0; k0 < K; k0 += 32) {
    const unsigned short* ga = A + (size_t)(m0 + srow) * K + k0 + scol;
    const unsigned short* gb = Bt + (size_t)(n0 + srow) * K + k0 + scol;
    gload16(ga, lA0);
    gload16(ga + (size_t)64 * K, lA1);
    gload16(gb, lB0);
    gload16(gb + (size_t)64 * K, lB1);
    __syncthreads();
    const short* pa = As + (wr * 64 + lrow) * 32 + lgrp * 8;
    const short* pb = Bs + (wc * 64 + lrow) * 32 + lgrp * 8;
    bf16x8 a[4], b[4];
#pragma unroll
    for (int m = 0; m < 4; ++m) a[m] = *(const bf16x8*)(pa + m * 512);
#pragma unroll
    for (int n = 0; n < 4; ++n) b[n] = *(const bf16x8*)(pb + n * 512);
#pragma unroll
    for (int m = 0; m < 4; ++m)
#pragma unroll
      for (int n = 0; n < 4; ++n)
        acc[m][n] = __builtin_amdgcn_mfma_f32_16x16x32_bf16(a[m], b[n], acc[m][n], 0, 0, 0);
    __syncthreads();
  }

#pragma unroll
  for (int n = 0; n < 4; ++n) {
    const int gn = n0 + wc * 64 + n * 16 + lrow;
    const float bv = bias[gn];
    if (MODE == 0) {
      unsigned short* out = (unsigned short*)outv;
      const int which = gn >> 10;
      const float qsc = (which == 0) ? QSCALE : 1.0f;
      const int e = gn & 1023;
      const int hh = e >> 6, dd = e & 63;
#pragma unroll
      for (int m = 0; m < 4; ++m)
#pragma unroll
        for (int r = 0; r < 4; ++r) {
          const int gm = m0 + wr * 64 + m * 16 + lgrp * 4 + r;
          const int t = gm >> 2, bb = gm & 3;  // A row index is t*B + b
          const unsigned short val = f2bf((acc[m][n][r] + bv) * qsc);
          const size_t rbase = ((size_t)which * 64 + bb * 16 + hh) * 131072;
          if (which == 0) {
            out[rbase + (size_t)t * 64 + dd] = val;
          } else if (which == 1) {
            out[rbase + (t >> 6) * 4096 +
                (((t >> 5) & 1) * 4 + (dd >> 4)) * 512 +
                ((((dd >> 3) & 1) << 5) + (t & 31)) * 8 + (dd & 7)] = val;
          } else {
            out[rbase + (t >> 6) * 4096 +
                ((dd >> 5) * 4 + ((t >> 4) & 3)) * 512 +
                ((((t >> 3) & 1) << 5) + (dd & 31)) * 8 + (t & 7)] = val;
          }
        }
    } else {
      float* out = (float*)outv;
#pragma unroll
      for (int m = 0; m < 4; ++m)
#pragma unroll
        for (int r = 0; r < 4; ++r) {
          const int gm = m0 + wr * 64 + m * 16 + lgrp * 4 + r;  // row = b*T + t
          const int bb = gm >> 11, t = gm & 2047;
          out[((size_t)t * B_DIM + bb) * E_DIM + gn] = acc[m][n][r] + bv;
        }
    }
  }
}

// ---------------- flash attention: 32x32 MFMA, zero P-LDS -------------------
// grid (T/128, B*H), 4 waves x 32 q-rows (q = lane&31). Fixed-max softmax.
// QK^T = mfma32(K,Q) -> C[k][q]; k = crow(reg,hi) = (reg&3)+8*(reg>>2)+4*hi.
// P redistributed IN-REGISTER to the PV B-fragment via pk_trunc pairs +
// v_permlane32_swap_b32 (swap(w0,w2), swap(w1,w3) per 16-k chunk) -- no P
// LDS round-trip. K/V/mask staged via identity-linear global_load_lds from
// fragment-permuted global layouts; every LDS read is lane-contiguous b128.
// Schedule: all 8 DMAs at iter start, vmcnt(0)+barrier at iter end (r17).
__global__ __launch_bounds__(256, 2) void attn_kernel(
    const unsigned short* __restrict__ Qm, const unsigned short* __restrict__ KPg,
    const unsigned short* __restrict__ VPg, const unsigned short* __restrict__ Mb,
    unsigned short* __restrict__ ctx) {
  __shared__ alignas(16) short Ks[2][4096];
  __shared__ alignas(16) short Vs[2][4096];
  __shared__ alignas(16) short Ml[2][8192];
  const int tid = threadIdx.x, lane = tid & 63, wave = tid >> 6;
  const int ql = lane & 31, hi = lane >> 5;
  const int bh = blockIdx.y, b = bh >> 4, h = bh & 15;
  const int q0 = blockIdx.x * 128;
  const int qrow = q0 + wave * 32 + ql;

  const size_t base = (size_t)bh * (T_DIM * EHD);
  const unsigned short* mbase = Mb + (size_t)blockIdx.x * 262144;

  bf16x8 qf[4];
#pragma unroll
  for (int i = 0; i < 4; ++i)
    qf[i] = *(const bf16x8*)(Qm + base + (size_t)qrow * 64 + i * 16 + hi * 8);

  f32x16 accO0 = {0.f, 0.f, 0.f, 0.f, 0.f, 0.f, 0.f, 0.f,
                  0.f, 0.f, 0.f, 0.f, 0.f, 0.f, 0.f, 0.f};
  f32x16 accO1 = accO0;
  float racc = 0.f;

#define STAGE(bufi, T_)                                                         \
  {                                                                             \
    _Pragma("unroll") for (int s2 = 0; s2 < 2; ++s2) {                          \
      const int s = wave * 2 + s2;                                              \
      gload16(KPg + base + (size_t)(T_) * 4096 + s * 512 + lane * 8,            \
              &Ks[bufi][s * 512]);                                              \
      gload16(VPg + base + (size_t)(T_) * 4096 + s * 512 + lane * 8,            \
              &Vs[bufi][s * 512]);                                              \
    }                                                                           \
    _Pragma("unroll") for (int u = 0; u < 4; ++u) {                             \
      const int s = wave * 4 + u;                                               \
      gload16(mbase + (size_t)(T_) * 8192 + s * 512 + lane * 8,                 \
              &Ml[bufi][s * 512]);                                              \
    }                                                                           \
  }

// one mask word -> 2 p values of ACC regs (HALF*8+2W, +1); pack into wk
#define SOFTW(ACC, KB, HALF, W, MW)                                             \
  {                                                                             \
    const f32x2 mm = bfpair1(MW);                                               \
    const f32x2 sv = {ACC[HALF * 8 + 2 * W], ACC[HALF * 8 + 2 * W + 1]};        \
    const f32x2 tt =                                                            \
        __builtin_elementwise_fma(sv, mm, (f32x2){-FMAXC, -FMAXC});             \
    const float p0 = __builtin_amdgcn_exp2f(tt.x);                              \
    const float p1 = __builtin_amdgcn_exp2f(tt.y);                              \
    racc += p0 + p1;                                                            \
    wk[KB][HALF * 4 + W] = pk_trunc(p0, p1);                                    \
  }

#define SOFTHALF(ACC, KB, HALF, MU)                                             \
  SOFTW(ACC, KB, HALF, 0, (MU).x)                                               \
  SOFTW(ACC, KB, HALF, 1, (MU).y)                                               \
  SOFTW(ACC, KB, HALF, 2, (MU).z)                                               \
  SOFTW(ACC, KB, HALF, 3, (MU).w)

// chunk (KB, HF): build PV B-frag via 2 permlane swaps, 2 MFMAs (dblk 0,1)
#define PVCHUNK(KB, HF)                                                         \
  {                                                                             \
    unsigned a0 = wk[KB][HF * 4 + 0], a1 = wk[KB][HF * 4 + 1];                  \
    unsigned a2 = wk[KB][HF * 4 + 2], a3 = wk[KB][HF * 4 + 3];                  \
    asm("v_permlane32_swap_b32 %0, %1" : "+v"(a0), "+v"(a2));                   \
    asm("v_permlane32_swap_b32 %0, %1" : "+v"(a1), "+v"(a3));                   \
    const u32x4 pw = {a0, a1, a2, a3};                                          \
    const bf16x8 pa = __builtin_bit_cast(bf16x8, pw);                           \
    const bf16x8 vf0 =                                                          \
        *(const bf16x8*)(vb + (0 + (KB)*2 + (HF)) * 512 + lane * 8);            \
    const bf16x8 vf1 =                                                          \
        *(const bf16x8*)(vb + (4 + (KB)*2 + (HF)) * 512 + lane * 8);            \
    accO0 = __builtin_amdgcn_mfma_f32_32x32x16_bf16(vf0, pa, accO0, 0, 0, 0);   \
    accO1 = __builtin_amdgcn_mfma_f32_32x32x16_bf16(vf1, pa, accO1, 0, 0, 0);   \
  }

#define ATTN_ITER(CUR, DO_PRE, TN)                                              \
  {                                                                             \
    if (DO_PRE) {                                                               \
      STAGE((CUR) ^ 1, TN);                                                     \
      __builtin_amdgcn_sched_barrier(0);                                        \
    }                                                                           \
    const short* kbl = Ks[CUR];                                                 \
    const short* vb = Vs[CUR];                                                  \
    const short* ml = Ml[CUR];                                                  \
    f32x16 accS0 = {0.f, 0.f, 0.f, 0.f, 0.f, 0.f, 0.f, 0.f,                     \
                    0.f, 0.f, 0.f, 0.f, 0.f, 0.f, 0.f, 0.f};                    \
    f32x16 accS1 = accS0;                                                       \
    __builtin_amdgcn_s_setprio(1);                                              \
    _Pragma("unroll") for (int i = 0; i < 4; ++i) {                             \
      const bf16x8 kf = *(const bf16x8*)(kbl + i * 512 + lane * 8);             \
      accS0 = __builtin_amdgcn_mfma_f32_32x32x16_bf16(kf, qf[i], accS0, 0, 0, 0); \
    }                                                                           \
    _Pragma("unroll") for (int i = 0; i < 4; ++i) {                             \
      const bf16x8 kf = *(const bf16x8*)(kbl + (4 + i) * 512 + lane * 8);       \
      accS1 = __builtin_amdgcn_mfma_f32_32x32x16_bf16(kf, qf[i], accS1, 0, 0, 0); \
    }                                                                           \
    __builtin_amdgcn_s_setprio(0);                                              \
    unsigned wk[2][8];                                                          \
    {                                                                           \
      const uint4 m0 = *(const uint4*)(ml + (wave * 4 + 0) * 512 + lane * 8);   \
      const uint4 m1 = *(const uint4*)(ml + (wave * 4 + 1) * 512 + lane * 8);   \
      SOFTHALF(accS0, 0, 0, m0)                                                 \
      SOFTHALF(accS0, 0, 1, m1)                                                 \
      const uint4 m2 = *(const uint4*)(ml + (wave * 4 + 2) * 512 + lane * 8);   \
      const uint4 m3 = *(const uint4*)(ml + (wave * 4 + 3) * 512 + lane * 8);   \
      SOFTHALF(accS1, 1, 0, m2)                                                 \
      SOFTHALF(accS1, 1, 1, m3)                                                 \
    }                                                                           \
    __builtin_amdgcn_s_setprio(1);                                              \
    PVCHUNK(0, 0)                                                               \
    PVCHUNK(0, 1)                                                               \
    PVCHUNK(1, 0)                                                               \
    PVCHUNK(1, 1)                                                               \
    __builtin_amdgcn_s_setprio(0);                                              \
  }

#define WAITBAR                                                                 \
  asm volatile("s_waitcnt vmcnt(0)" ::: "memory");                              \
  __builtin_amdgcn_sched_barrier(0);                                            \
  __builtin_amdgcn_s_barrier();                                                 \
  __builtin_amdgcn_sched_barrier(0);

  STAGE(0, 0);
  WAITBAR

  for (int tt = 0; tt < 15; ++tt) {
    ATTN_ITER(0, 1, 2 * tt + 1);
    WAITBAR
    ATTN_ITER(1, 1, 2 * tt + 2);
    WAITBAR
  }
  ATTN_ITER(0, 1, 31);
  WAITBAR
  ATTN_ITER(1, 0, 0);

#undef ATTN_ITER
#undef WAITBAR
#undef STAGE
#undef PVCHUNK
#undef SOFTHALF
#undef SOFTW

  racc += __shfl_xor(racc, 32);
  const float inv = 1.f / racc;
  unsigned short* cp =
      ctx + ((size_t)b * T_DIM + qrow) * E_DIM + h * 64 + hi * 4;
#define EPI(ACC, DBLK)                                                          \
  _Pragma("unroll") for (int rg = 0; rg < 4; ++rg) {                            \
    uint2 w;                                                                    \
    w.x = pkbf(ACC[rg * 4 + 0] * inv, ACC[rg * 4 + 1] * inv);                   \
    w.y = pkbf(ACC[rg * 4 + 2] * inv, ACC[rg * 4 + 3] * inv);                   \
    *(uint2*)(cp + (DBLK)*32 + rg * 8) = w;                                     \
  }
  EPI(accO0, 0)
  EPI(accO1, 1)
#undef EPI
}

extern "C" void kernel_launch(void* const* d_in, const int* in_sizes, int n_in,
                              void* d_out, int out_size, void* d_ws, size_t ws_size,
                              hipStream_t stream) {
  const float* q    = (const float*)d_in[0];
  const float* k    = (const float*)d_in[1];
  const float* v    = (const float*)d_in[2];
  const float* mask = (const float*)d_in[3];
  const float* wqkv = (const float*)d_in[4];
  const float* bqkv = (const float*)d_in[5];
  const float* wout = (const float*)d_in[6];
  const float* bout = (const float*)d_in[7];

  char* ws = (char*)d_ws;
  unsigned short* Xb   = (unsigned short*)(ws);
  unsigned short* Wqb  = (unsigned short*)(ws + 50331648);
  unsigned short* Wob  = (unsigned short*)(ws + 56623104);
  unsigned short* QKVb = (unsigned short*)(ws + 58720256);  // [Q|KP|VP] bf16
  unsigned short* CTXb = (unsigned short*)(ws);             // [B][T][E] (Xb dead)
  unsigned short* Mb   = (unsigned short*)(ws + 16777216);  // permuted bf16 mask

  cvt_fused<<<2048, 256, 0, stream>>>(
      (const float4*)q, (const float4*)k, (const float4*)v,
      (const float4*)wqkv, (const float4*)wout, (uint2*)Xb,
      (uint2*)(Xb + 8388608), (uint2*)(Xb + 16777216), (uint2*)Wqb,
      (uint2*)Wob);

  gemm_kernel<0><<<dim3(64, 24), 256, 0, stream>>>(Xb, Wqb, bqkv, QKVb, 1024);
  // mask -> permuted bf16 AFTER GEMM1 (Mb lives in the then-dead Xb region)
  mask_perm<<<2048, 256, 0, stream>>>(mask, (uint4*)Mb);
  attn_kernel<<<dim3(16, 64), 256, 0, stream>>>(QKVb, QKVb + 8388608,
                                                QKVb + 16777216, Mb, CTXb);
  gemm_kernel<1><<<dim3(64, 8), 256, 0, stream>>>(CTXb, Wob, bout, d_out, 1024);
}

// Round 19
// 254.777 us; speedup vs baseline: 1.7388x; 1.0020x over previous
//
#include <hip/hip_runtime.h>
#include <hip/hip_bf16.h>
#include <stdint.h>

#define T_DIM 2048
#define B_DIM 4
#define E_DIM 1024
#define H_DIM 16
#define EHD 64
#define L2E 1.4426950408889634f
#define QSCALE (0.125f * L2E)
#define FMAXC 12.0f

typedef __attribute__((ext_vector_type(8))) short bf16x8;
typedef __attribute__((ext_vector_type(4))) float f32x4;
typedef __attribute__((ext_vector_type(16))) float f32x16;
typedef __attribute__((ext_vector_type(2))) float f32x2;
typedef __attribute__((ext_vector_type(2))) unsigned u32x2;
typedef __attribute__((ext_vector_type(4))) unsigned u32x4;

__device__ __forceinline__ unsigned short f2bf(float x) {
  unsigned int u = __builtin_bit_cast(unsigned int, x);
  u += 0x7fffu + ((u >> 16) & 1u);
  return (unsigned short)(u >> 16);
}

__device__ __forceinline__ unsigned pkbf(float a, float b) {
  return (unsigned)f2bf(a) | ((unsigned)f2bf(b) << 16);
}

// truncation pack (P hot path only; bias cancels in sum(pV)/sum(p))
__device__ __forceinline__ unsigned pk_trunc(float a, float b) {
  return (__builtin_bit_cast(unsigned, a) >> 16) |
         (__builtin_bit_cast(unsigned, b) & 0xffff0000u);
}

// expand packed bf16 pair (lo, hi) -> f32x2
__device__ __forceinline__ f32x2 bfpair1(unsigned w) {
  u32x2 u = {w << 16, w & 0xffff0000u};
  return __builtin_bit_cast(f32x2, u);
}

__device__ __forceinline__ void gload16(const void* g, void* l) {
  __builtin_amdgcn_global_load_lds(
      (const __attribute__((address_space(1))) void*)g,
      (__attribute__((address_space(3))) void*)l, 16, 0, 0);
}

// ---------------- fused fp32 -> bf16 for all 5 inputs (1 launch) ------------
__global__ __launch_bounds__(256) void cvt_fused(
    const float4* __restrict__ q, const float4* __restrict__ k,
    const float4* __restrict__ v, const float4* __restrict__ wqkv,
    const float4* __restrict__ wout, uint2* __restrict__ xq,
    uint2* __restrict__ xk, uint2* __restrict__ xv, uint2* __restrict__ wq,
    uint2* __restrict__ wo) {
  int i = blockIdx.x * 256 + threadIdx.x;
  const int stride = gridDim.x * 256;
  for (; i < 7340032; i += stride) {
    const float4* s;
    uint2* d;
    int j;
    if (i < 2097152) { s = q; d = xq; j = i; }
    else if (i < 4194304) { s = k; d = xk; j = i - 2097152; }
    else if (i < 6291456) { s = v; d = xv; j = i - 4194304; }
    else if (i < 7077888) { s = wqkv; d = wq; j = i - 6291456; }
    else { s = wout; d = wo; j = i - 7077888; }
    const float4 f = s[j];
    uint2 o;
    o.x = pkbf(f.x, f.y);
    o.y = pkbf(f.z, f.w);
    d[j] = o;
  }
}

// ---------------- mask fp32 -> bf16, permuted to 32x32 C-fragment order -----
// uint4 index c = ((((qblk*32+t)*4+wave)*2+kb)*2+half)*64+lane.
// Holds mask for q = qblk*128+wave*32+(lane&31),
// k = t*64 + kb*32 + 16*half + 4*(lane>>5) + {0,1,2,3, 8,9,10,11} (rr order).
__global__ __launch_bounds__(256) void mask_perm(const float* __restrict__ mask,
                                                 uint4* __restrict__ out) {
  const int c = blockIdx.x * 256 + threadIdx.x;  // grid 2048*256 = 524288 exact
  const int lane = c & 63;
  const int half = (c >> 6) & 1;
  const int kb = (c >> 7) & 1;
  const int wave = (c >> 8) & 3;
  const int t = (c >> 10) & 31;
  const int qblk = c >> 15;
  const int hi = lane >> 5;
  const int qq = qblk * 128 + wave * 32 + (lane & 31);
  const int kbase = t * 64 + kb * 32 + half * 16 + hi * 4;
  const float4 f0 = *(const float4*)(mask + (size_t)qq * T_DIM + kbase);
  const float4 f1 = *(const float4*)(mask + (size_t)qq * T_DIM + kbase + 8);
  uint4 o;
  o.x = pkbf(f0.x, f0.y);
  o.y = pkbf(f0.z, f0.w);
  o.z = pkbf(f1.x, f1.y);
  o.w = pkbf(f1.z, f1.w);
  out[c] = o;
}

// ---------------- 128x128 bf16 NT GEMM (m97 structure) ----------------
// MODE 0: QKV proj. Q third pre-scaled, row-major [bh][t][d].
//         K third -> fragment-permuted KP; V third -> fragment-permuted VP.
// MODE 1: out projection -> FP32 out[(t*B+b)*E + n].
template <int MODE>
__global__ __launch_bounds__(256) void gemm_kernel(
    const unsigned short* __restrict__ Abase,
    const unsigned short* __restrict__ Bt,
    const float* __restrict__ bias,
    void* __restrict__ outv, int K) {
  __shared__ alignas(16) short As[128 * 32];
  __shared__ alignas(16) short Bs[128 * 32];
  const int tid = threadIdx.x;
  const int lane = tid & 63, wave = tid >> 6;
  const int m0 = blockIdx.x * 128, n0 = blockIdx.y * 128;
  const int wr = wave >> 1, wc = wave & 1;
  const int lrow = lane & 15, lgrp = lane >> 4;

  const unsigned short* A = Abase;
  if (MODE == 0) A += (size_t)(n0 >> 10) * (8192u * 1024u);

  f32x4 acc[4][4];
#pragma unroll
  for (int m = 0; m < 4; ++m)
#pragma unroll
    for (int n = 0; n < 4; ++n) acc[m][n] = (f32x4){0.f, 0.f, 0.f, 0.f};

  const int srow = wave * 16 + (lane >> 2);
  const int scol = (lane & 3) * 8;
  short* lA0 = As + wave * 16 * 32;
  short* lA1 = As + (64 + wave * 16) * 32;
  short* lB0 = Bs + wave * 16 * 32;
  short* lB1 = Bs + (64 + wave * 16) * 32;

  for (int k0 = 0; k0 < K; k0 += 32) {
    const unsigned short* ga = A + (size_t)(m0 + srow) * K + k0 + scol;
    const unsigned short* gb = Bt + (size_t)(n0 + srow) * K + k0 + scol;
    gload16(ga, lA0);
    gload16(ga + (size_t)64 * K, lA1);
    gload16(gb, lB0);
    gload16(gb + (size_t)64 * K, lB1);
    __syncthreads();
    const short* pa = As + (wr * 64 + lrow) * 32 + lgrp * 8;
    const short* pb = Bs + (wc * 64 + lrow) * 32 + lgrp * 8;
    bf16x8 a[4], b[4];
#pragma unroll
    for (int m = 0; m < 4; ++m) a[m] = *(const bf16x8*)(pa + m * 512);
#pragma unroll
    for (int n = 0; n < 4; ++n) b[n] = *(const bf16x8*)(pb + n * 512);
#pragma unroll
    for (int m = 0; m < 4; ++m)
#pragma unroll
      for (int n = 0; n < 4; ++n)
        acc[m][n] = __builtin_amdgcn_mfma_f32_16x16x32_bf16(a[m], b[n], acc[m][n], 0, 0, 0);
    __syncthreads();
  }

#pragma unroll
  for (int n = 0; n < 4; ++n) {
    const int gn = n0 + wc * 64 + n * 16 + lrow;
    const float bv = bias[gn];
    if (MODE == 0) {
      unsigned short* out = (unsigned short*)outv;
      const int which = gn >> 10;
      const float qsc = (which == 0) ? QSCALE : 1.0f;
      const int e = gn & 1023;
      const int hh = e >> 6, dd = e & 63;
#pragma unroll
      for (int m = 0; m < 4; ++m)
#pragma unroll
        for (int r = 0; r < 4; ++r) {
          const int gm = m0 + wr * 64 + m * 16 + lgrp * 4 + r;
          const int t = gm >> 2, bb = gm & 3;  // A row index is t*B + b
          const unsigned short val = f2bf((acc[m][n][r] + bv) * qsc);
          const size_t rbase = ((size_t)which * 64 + bb * 16 + hh) * 131072;
          if (which == 0) {
            out[rbase + (size_t)t * 64 + dd] = val;
          } else if (which == 1) {
            out[rbase + (t >> 6) * 4096 +
                (((t >> 5) & 1) * 4 + (dd >> 4)) * 512 +
                ((((dd >> 3) & 1) << 5) + (t & 31)) * 8 + (dd & 7)] = val;
          } else {
            out[rbase + (t >> 6) * 4096 +
                ((dd >> 5) * 4 + ((t >> 4) & 3)) * 512 +
                ((((t >> 3) & 1) << 5) + (dd & 31)) * 8 + (t & 7)] = val;
          }
        }
    } else {
      float* out = (float*)outv;
#pragma unroll
      for (int m = 0; m < 4; ++m)
#pragma unroll
        for (int r = 0; r < 4; ++r) {
          const int gm = m0 + wr * 64 + m * 16 + lgrp * 4 + r;  // row = b*T + t
          const int bb = gm >> 11, t = gm & 2047;
          out[((size_t)t * B_DIM + bb) * E_DIM + gn] = acc[m][n][r] + bv;
        }
    }
  }
}

// ---------------- flash attention: 32x32 MFMA, mask in registers ------------
// grid (T/128, B*H), 4 waves x 32 q-rows (q = lane&31). Fixed-max softmax.
// Round 19: mask moves from LDS back to REGISTERS -- the permuted layout
// makes register loads lane-contiguous (same TA cost as DMA), freeing 32KB
// LDS (64->32KB => 3 blocks/CU) and deleting 8 mask ds_reads/wave-iter.
// Mask regs double-buffered (uint4 x4/wave), issued with STAGE at iter start,
// retired by the end-of-iter vmcnt(0); they survive the barrier in VGPRs.
// P stays in-register via pk_trunc + v_permlane32_swap_b32 (round 18).
__global__ __launch_bounds__(256, 3) void attn_kernel(
    const unsigned short* __restrict__ Qm, const unsigned short* __restrict__ KPg,
    const unsigned short* __restrict__ VPg, const unsigned short* __restrict__ Mb,
    unsigned short* __restrict__ ctx) {
  __shared__ alignas(16) short Ks[2][4096];
  __shared__ alignas(16) short Vs[2][4096];
  const int tid = threadIdx.x, lane = tid & 63, wave = tid >> 6;
  const int ql = lane & 31, hi = lane >> 5;
  const int bh = blockIdx.y, b = bh >> 4, h = bh & 15;
  const int q0 = blockIdx.x * 128;
  const int qrow = q0 + wave * 32 + ql;

  const size_t base = (size_t)bh * (T_DIM * EHD);
  const uint4* mb4 = (const uint4*)Mb + (size_t)blockIdx.x * 32768 +
                     wave * 256 + lane;  // + tile*1024 + u*64

  bf16x8 qf[4];
#pragma unroll
  for (int i = 0; i < 4; ++i)
    qf[i] = *(const bf16x8*)(Qm + base + (size_t)qrow * 64 + i * 16 + hi * 8);

  f32x16 accO0 = {0.f, 0.f, 0.f, 0.f, 0.f, 0.f, 0.f, 0.f,
                  0.f, 0.f, 0.f, 0.f, 0.f, 0.f, 0.f, 0.f};
  f32x16 accO1 = accO0;
  f32x2 racc2 = {0.f, 0.f};

  uint4 mreg[2][4];  // [tile parity][u = kb*2+half] -- static indices

#define STAGE(bufi, T_)                                                         \
  {                                                                             \
    _Pragma("unroll") for (int s2 = 0; s2 < 2; ++s2) {                          \
      const int s = wave * 2 + s2;                                              \
      gload16(KPg + base + (size_t)(T_) * 4096 + s * 512 + lane * 8,            \
              &Ks[bufi][s * 512]);                                              \
      gload16(VPg + base + (size_t)(T_) * 4096 + s * 512 + lane * 8,            \
              &Vs[bufi][s * 512]);                                              \
    }                                                                           \
    _Pragma("unroll") for (int u = 0; u < 4; ++u) {                             \
      mreg[bufi][u] = mb4[(size_t)(T_) * 1024 + u * 64];                        \
    }                                                                           \
  }

// one mask word -> 2 p values of ACC regs (HALF*8+2W, +1); pack into wk
#define SOFTW(ACC, KB, HALF, W, MW)                                             \
  {                                                                             \
    const f32x2 mm = bfpair1(MW);                                               \
    const f32x2 sv = {ACC[HALF * 8 + 2 * W], ACC[HALF * 8 + 2 * W + 1]};        \
    const f32x2 tt =                                                            \
        __builtin_elementwise_fma(sv, mm, (f32x2){-FMAXC, -FMAXC});             \
    const float p0 = __builtin_amdgcn_exp2f(tt.x);                              \
    const float p1 = __builtin_amdgcn_exp2f(tt.y);                              \
    racc2 += (f32x2){p0, p1};                                                   \
    wk[KB][HALF * 4 + W] = pk_trunc(p0, p1);                                    \
  }

#define SOFTHALF(ACC, KB, HALF, MU)                                             \
  SOFTW(ACC, KB, HALF, 0, (MU).x)                                               \
  SOFTW(ACC, KB, HALF, 1, (MU).y)                                               \
  SOFTW(ACC, KB, HALF, 2, (MU).z)                                               \
  SOFTW(ACC, KB, HALF, 3, (MU).w)

// chunk (KB, HF): build PV B-frag via 2 permlane swaps, 2 MFMAs (dblk 0,1)
#define PVCHUNK(KB, HF)                                                         \
  {                                                                             \
    unsigned a0 = wk[KB][HF * 4 + 0], a1 = wk[KB][HF * 4 + 1];                  \
    unsigned a2 = wk[KB][HF * 4 + 2], a3 = wk[KB][HF * 4 + 3];                  \
    asm("v_permlane32_swap_b32 %0, %1" : "+v"(a0), "+v"(a2));                   \
    asm("v_permlane32_swap_b32 %0, %1" : "+v"(a1), "+v"(a3));                   \
    const u32x4 pw = {a0, a1, a2, a3};                                          \
    const bf16x8 pa = __builtin_bit_cast(bf16x8, pw);                           \
    const bf16x8 vf0 =                                                          \
        *(const bf16x8*)(vb + (0 + (KB)*2 + (HF)) * 512 + lane * 8);            \
    const bf16x8 vf1 =                                                          \
        *(const bf16x8*)(vb + (4 + (KB)*2 + (HF)) * 512 + lane * 8);            \
    accO0 = __builtin_amdgcn_mfma_f32_32x32x16_bf16(vf0, pa, accO0, 0, 0, 0);   \
    accO1 = __builtin_amdgcn_mfma_f32_32x32x16_bf16(vf1, pa, accO1, 0, 0, 0);   \
  }

#define ATTN_ITER(CUR, DO_PRE, TN)                                              \
  {                                                                             \
    if (DO_PRE) {                                                               \
      STAGE((CUR) ^ 1, TN);                                                     \
      __builtin_amdgcn_sched_barrier(0);                                        \
    }                                                                           \
    const short* kbl = Ks[CUR];                                                 \
    const short* vb = Vs[CUR];                                                  \
    f32x16 accS0 = {0.f, 0.f, 0.f, 0.f, 0.f, 0.f, 0.f, 0.f,                     \
                    0.f, 0.f, 0.f, 0.f, 0.f, 0.f, 0.f, 0.f};                    \
    f32x16 accS1 = accS0;                                                       \
    __builtin_amdgcn_s_setprio(1);                                              \
    _Pragma("unroll") for (int i = 0; i < 4; ++i) {                             \
      const bf16x8 kf = *(const bf16x8*)(kbl + i * 512 + lane * 8);             \
      accS0 = __builtin_amdgcn_mfma_f32_32x32x16_bf16(kf, qf[i], accS0, 0, 0, 0); \
    }                                                                           \
    _Pragma("unroll") for (int i = 0; i < 4; ++i) {                             \
      const bf16x8 kf = *(const bf16x8*)(kbl + (4 + i) * 512 + lane * 8);       \
      accS1 = __builtin_amdgcn_mfma_f32_32x32x16_bf16(kf, qf[i], accS1, 0, 0, 0); \
    }                                                                           \
    __builtin_amdgcn_s_setprio(0);                                              \
    unsigned wk[2][8];                                                          \
    SOFTHALF(accS0, 0, 0, mreg[CUR][0])                                         \
    SOFTHALF(accS0, 0, 1, mreg[CUR][1])                                         \
    SOFTHALF(accS1, 1, 0, mreg[CUR][2])                                         \
    SOFTHALF(accS1, 1, 1, mreg[CUR][3])                                         \
    __builtin_amdgcn_s_setprio(1);                                              \
    PVCHUNK(0, 0)                                                               \
    PVCHUNK(0, 1)                                                               \
    PVCHUNK(1, 0)                                                               \
    PVCHUNK(1, 1)                                                               \
    __builtin_amdgcn_s_setprio(0);                                              \
  }

#define WAITBAR                                                                 \
  asm volatile("s_waitcnt vmcnt(0)" ::: "memory");                              \
  __builtin_amdgcn_sched_barrier(0);                                            \
  __builtin_amdgcn_s_barrier();                                                 \
  __builtin_amdgcn_sched_barrier(0);

  STAGE(0, 0);
  WAITBAR

  for (int tt = 0; tt < 15; ++tt) {
    ATTN_ITER(0, 1, 2 * tt + 1);
    WAITBAR
    ATTN_ITER(1, 1, 2 * tt + 2);
    WAITBAR
  }
  ATTN_ITER(0, 1, 31);
  WAITBAR
  ATTN_ITER(1, 0, 0);

#undef ATTN_ITER
#undef WAITBAR
#undef STAGE
#undef PVCHUNK
#undef SOFTHALF
#undef SOFTW

  float racc = racc2.x + racc2.y;
  racc += __shfl_xor(racc, 32);
  const float inv = 1.f / racc;
  unsigned short* cp =
      ctx + ((size_t)b * T_DIM + qrow) * E_DIM + h * 64 + hi * 4;
#define EPI(ACC, DBLK)                                                          \
  _Pragma("unroll") for (int rg = 0; rg < 4; ++rg) {                            \
    uint2 w;                                                                    \
    w.x = pkbf(ACC[rg * 4 + 0] * inv, ACC[rg * 4 + 1] * inv);                   \
    w.y = pkbf(ACC[rg * 4 + 2] * inv, ACC[rg * 4 + 3] * inv);                   \
    *(uint2*)(cp + (DBLK)*32 + rg * 8) = w;                                     \
  }
  EPI(accO0, 0)
  EPI(accO1, 1)
#undef EPI
}

extern "C" void kernel_launch(void* const* d_in, const int* in_sizes, int n_in,
                              void* d_out, int out_size, void* d_ws, size_t ws_size,
                              hipStream_t stream) {
  const float* q    = (const float*)d_in[0];
  const float* k    = (const float*)d_in[1];
  const float* v    = (const float*)d_in[2];
  const float* mask = (const float*)d_in[3];
  const float* wqkv = (const float*)d_in[4];
  const float* bqkv = (const float*)d_in[5];
  const float* wout = (const float*)d_in[6];
  const float* bout = (const float*)d_in[7];

  char* ws = (char*)d_ws;
  unsigned short* Xb   = (unsigned short*)(ws);
  unsigned short* Wqb  = (unsigned short*)(ws + 50331648);
  unsigned short* Wob  = (unsigned short*)(ws + 56623104);
  unsigned short* QKVb = (unsigned short*)(ws + 58720256);  // [Q|KP|VP] bf16
  unsigned short* CTXb = (unsigned short*)(ws);             // [B][T][E] (Xb dead)
  unsigned short* Mb   = (unsigned short*)(ws + 16777216);  // permuted bf16 mask

  cvt_fused<<<2048, 256, 0, stream>>>(
      (const float4*)q, (const float4*)k, (const float4*)v,
      (const float4*)wqkv, (const float4*)wout, (uint2*)Xb,
      (uint2*)(Xb + 8388608), (uint2*)(Xb + 16777216), (uint2*)Wqb,
      (uint2*)Wob);

  gemm_kernel<0><<<dim3(64, 24), 256, 0, stream>>>(Xb, Wqb, bqkv, QKVb, 1024);
  // mask -> permuted bf16 AFTER GEMM1 (Mb lives in the then-dead Xb region)
  mask_perm<<<2048, 256, 0, stream>>>(mask, (uint4*)Mb);
  attn_kernel<<<dim3(16, 64), 256, 0, stream>>>(QKVb, QKVb + 8388608,
                                                QKVb + 16777216, Mb, CTXb);
  gemm_kernel<1><<<dim3(64, 8), 256, 0, stream>>>(CTXb, Wob, bout, d_out, 1024);
}